// Round 3
// baseline (2815.175 us; speedup 1.0000x reference)
//
#include <hip/hip_runtime.h>
#include <hip/hip_bf16.h>
#include <math.h>

// ---------------------------------------------------------------------------
// MoE trading transformer forward, MI355X/gfx950.
// B=16 S=512 F_IN=46 D=256 H=8 (dh=32) L=6 E=8 DFF=1024 OUT=3.
// R3: top-2 sparse MoE routing (math-identical to dense reference: unrouted
// experts have weight 0) + attention bank-conflict / V-staging fix.
//
// Workspace (~39.9 MB, < 40.6 MB proven available in R2):
//   [0]          h        bf16 8193x256 (row 8192 = pad-token scratch)
//   [4.25M]      moe      bf16 8193x256 (row 8192 = scratch)
//   [8.5M]       ctrl: auxs|cnt|pos|flag|seg_off|ntiles|tile_ex|ostage|
//                      top_e|top_w|list|lw   (~283 KB)
//   [9.5M] big:  qkv bf16 8192x768 (12M) | aout (4M) ; reused as projo(4M),
//                then hid bf16 9216x1024 (18.9M, compacted rows)
//   [28M]        pattn, pooled
//   [28.02M]     cvbase: canonical bf16 copies of all 41 inputs (~10.1M)
// ---------------------------------------------------------------------------

typedef __bf16 bf16;
typedef __bf16 bf16x8 __attribute__((ext_vector_type(8)));
typedef float f32x4 __attribute__((ext_vector_type(4)));

#define NIN 41

struct InTab {
    const void* src[NIN];
    unsigned off[NIN];
    unsigned n[NIN];
};

__device__ __forceinline__ float gelu_exact(float x) {
    return 0.5f * x * (1.0f + erff(x * 0.70710678118654752f));
}

// ---------------------------------------------------------------------------
// Dtype sniffer (f32 vs bf16 storage), as in R2. flag: 1=bf16, 0=f32.
// ---------------------------------------------------------------------------
__global__ void sniff_kernel(const unsigned* __restrict__ xw, int* __restrict__ flag) {
    __shared__ int cnt;
    if (threadIdx.x == 0) cnt = 0;
    __syncthreads();
    const unsigned w = xw[threadIdx.x];
    const unsigned ex = (w >> 7) & 0xFFu;
    if (ex >= 107u && ex <= 133u) atomicAdd(&cnt, 1);
    __syncthreads();
    if (threadIdx.x == 0) *flag = (cnt >= 192) ? 1 : 0;
}

__global__ __launch_bounds__(256) void convert_kernel(
    InTab tab, bf16* __restrict__ dst_base, const int* __restrict__ flag) {
    const int inp = blockIdx.y;
    const unsigned n = tab.n[inp];
    const unsigned i0 = (blockIdx.x * 256u + threadIdx.x) * 4u;
    if (i0 >= n) return;
    const int isbf = *flag;
    bf16* dst = dst_base + tab.off[inp];
    const unsigned end = (i0 + 4u > n) ? n : i0 + 4u;
    if (isbf) {
        const unsigned short* s = (const unsigned short*)tab.src[inp];
        for (unsigned i = i0; i < end; i++) ((unsigned short*)dst)[i] = s[i];
    } else {
        const float* s = (const float*)tab.src[inp];
        for (unsigned i = i0; i < end; i++) dst[i] = (bf16)s[i];
    }
}

__global__ void out_convert_kernel(const float* __restrict__ st, void* __restrict__ out,
                                   const int* __restrict__ flag) {
    const int i = threadIdx.x;
    if (i >= 65) return;
    if (*flag) ((bf16*)out)[i] = (bf16)st[i];
    else       ((float*)out)[i] = st[i];
}

// ---------------------------------------------------------------------------
// Dense MFMA GEMM (qkv / out-proj):  C[M,N] = A[M,K] @ W[N,K]^T + bias[N]
// ---------------------------------------------------------------------------
template <int BM, int BN, int WM, int WN>
__global__ __launch_bounds__(256) void gemm_bt(
    const bf16* __restrict__ A, const bf16* __restrict__ W,
    const bf16* __restrict__ bias, bf16* __restrict__ C,
    int M, int N, int K) {
    constexpr int BK = 64;
    __shared__ alignas(16) bf16 As[BM][BK + 8];
    __shared__ alignas(16) bf16 Ws[BN][BK + 8];
    const int bm0 = blockIdx.x * BM, bn0 = blockIdx.y * BN;
    const int tid = threadIdx.x;
    const int wave = tid >> 6, lane = tid & 63;
    constexpr int WCOLS = BN / WN;
    const int wm0 = (wave / WCOLS) * WM, wn0 = (wave % WCOLS) * WN;
    constexpr int MT = WM / 16, NT = WN / 16;
    f32x4 acc[MT][NT] = {};
    const int lrow = tid >> 3, lcol = (tid & 7) * 8;
    const int frow = lane & 15, fquad = lane >> 4;

    for (int k0 = 0; k0 < K; k0 += BK) {
#pragma unroll
        for (int p = 0; p < BM / 32; p++)
            *(bf16x8*)&As[lrow + p * 32][lcol] =
                *(const bf16x8*)&A[(size_t)(bm0 + lrow + p * 32) * K + k0 + lcol];
#pragma unroll
        for (int p = 0; p < BN / 32; p++)
            *(bf16x8*)&Ws[lrow + p * 32][lcol] =
                *(const bf16x8*)&W[(size_t)(bn0 + lrow + p * 32) * K + k0 + lcol];
        __syncthreads();
#pragma unroll
        for (int ks = 0; ks < BK / 32; ks++) {
            bf16x8 af[MT], bfr[NT];
#pragma unroll
            for (int mt = 0; mt < MT; mt++)
                af[mt] = *(const bf16x8*)&As[wm0 + mt * 16 + frow][ks * 32 + fquad * 8];
#pragma unroll
            for (int nt = 0; nt < NT; nt++)
                bfr[nt] = *(const bf16x8*)&Ws[wn0 + nt * 16 + frow][ks * 32 + fquad * 8];
#pragma unroll
            for (int mt = 0; mt < MT; mt++)
#pragma unroll
                for (int nt = 0; nt < NT; nt++)
                    acc[mt][nt] = __builtin_amdgcn_mfma_f32_16x16x32_bf16(
                        af[mt], bfr[nt], acc[mt][nt], 0, 0, 0);
        }
        __syncthreads();
    }

#pragma unroll
    for (int mt = 0; mt < MT; mt++)
#pragma unroll
        for (int nt = 0; nt < NT; nt++) {
            const int gn = bn0 + wn0 + nt * 16 + frow;
            const float bv = (float)bias[gn];
#pragma unroll
            for (int r = 0; r < 4; r++) {
                const int gm = bm0 + wm0 + mt * 16 + fquad * 4 + r;
                C[(size_t)gm * N + gn] = (bf16)(acc[mt][nt][r] + bv);
            }
        }
}

// ---------------------------------------------------------------------------
// Routed MoE GEMM over a compacted token list (one launch per slot).
// MODE 1: w1  hid[i] = GELU(h[list[i]] @ w1_e^T + b1_e)      (N=1024,K=256)
// MODE 2: w2  moe[list[i]]  = lw[i]*(hid[i] @ w2_e^T + b2_e) (N=256, K=1024)
// MODE 3: w2  moe[list[i]] += lw[i]*(...)
// Per-tile expert id from tile_ex; blocks beyond *ntiles exit.
// Pad rows have list[i]=8192 (scratch row), lw[i]=0.
// ---------------------------------------------------------------------------
template <int BM, int BN, int WM, int WN, int MODE>
__global__ __launch_bounds__(256) void gemm_moe(
    const bf16* __restrict__ A, const bf16* __restrict__ Wb,
    const bf16* __restrict__ biasb, bf16* __restrict__ C,
    int N, int K, const int* __restrict__ list, const float* __restrict__ lw,
    const int* __restrict__ tile_ex, const int* __restrict__ ntiles) {
    if ((int)blockIdx.x >= *ntiles) return;
    constexpr int BK = 64;
    __shared__ alignas(16) bf16 As[BM][BK + 8];
    __shared__ alignas(16) bf16 Ws[BN][BK + 8];
    const int e = tile_ex[blockIdx.x];
    const bf16* W = Wb + (size_t)e * N * K;
    const bf16* bias = biasb + e * N;
    const int bm0 = blockIdx.x * BM, bn0 = blockIdx.y * BN;
    const int tid = threadIdx.x;
    const int wave = tid >> 6, lane = tid & 63;
    constexpr int WCOLS = BN / WN;
    const int wm0 = (wave / WCOLS) * WM, wn0 = (wave % WCOLS) * WN;
    constexpr int MT = WM / 16, NT = WN / 16;
    f32x4 acc[MT][NT] = {};
    const int lrow = tid >> 3, lcol = (tid & 7) * 8;
    const int frow = lane & 15, fquad = lane >> 4;

    int arow[BM / 32];
#pragma unroll
    for (int p = 0; p < BM / 32; p++) {
        const int r = bm0 + lrow + p * 32;
        arow[p] = (MODE == 1) ? list[r] : r;
    }

    for (int k0 = 0; k0 < K; k0 += BK) {
#pragma unroll
        for (int p = 0; p < BM / 32; p++)
            *(bf16x8*)&As[lrow + p * 32][lcol] =
                *(const bf16x8*)&A[(size_t)arow[p] * K + k0 + lcol];
#pragma unroll
        for (int p = 0; p < BN / 32; p++)
            *(bf16x8*)&Ws[lrow + p * 32][lcol] =
                *(const bf16x8*)&W[(size_t)(bn0 + lrow + p * 32) * K + k0 + lcol];
        __syncthreads();
#pragma unroll
        for (int ks = 0; ks < BK / 32; ks++) {
            bf16x8 af[MT], bfr[NT];
#pragma unroll
            for (int mt = 0; mt < MT; mt++)
                af[mt] = *(const bf16x8*)&As[wm0 + mt * 16 + frow][ks * 32 + fquad * 8];
#pragma unroll
            for (int nt = 0; nt < NT; nt++)
                bfr[nt] = *(const bf16x8*)&Ws[wn0 + nt * 16 + frow][ks * 32 + fquad * 8];
#pragma unroll
            for (int mt = 0; mt < MT; mt++)
#pragma unroll
                for (int nt = 0; nt < NT; nt++)
                    acc[mt][nt] = __builtin_amdgcn_mfma_f32_16x16x32_bf16(
                        af[mt], bfr[nt], acc[mt][nt], 0, 0, 0);
        }
        __syncthreads();
    }

#pragma unroll
    for (int mt = 0; mt < MT; mt++)
#pragma unroll
        for (int nt = 0; nt < NT; nt++) {
            const int gn = bn0 + wn0 + nt * 16 + frow;
            const float bv = (float)bias[gn];
#pragma unroll
            for (int r = 0; r < 4; r++) {
                const int gm = bm0 + wm0 + mt * 16 + fquad * 4 + r;
                const float v = acc[mt][nt][r] + bv;
                if (MODE == 1) {
                    C[(size_t)gm * N + gn] = (bf16)gelu_exact(v);
                } else {
                    const int token = list[gm];
                    const float s = lw[gm];
                    bf16* dst = &C[(size_t)token * 256 + gn];
                    if (MODE == 2) *dst = (bf16)(s * v);
                    else           *dst = (bf16)((float)*dst + s * v);
                }
            }
        }
}

// ---------------------------------------------------------------------------
// Input projection + positional encoding. grid 8192, block 256.
// ---------------------------------------------------------------------------
__global__ __launch_bounds__(256) void input_proj_kernel(
    const bf16* __restrict__ x, const bf16* __restrict__ w,
    const bf16* __restrict__ b, bf16* __restrict__ h) {
    const int m = blockIdx.x, t = threadIdx.x;
    __shared__ float xs[46];
    if (t < 46) xs[t] = (float)x[m * 46 + t];
    __syncthreads();
    float acc = (float)b[t];
#pragma unroll
    for (int k = 0; k < 46; k++) acc += xs[k] * (float)w[t * 46 + k];
    const int s = m & 511;
    const int i = t >> 1;
    const float dv = expf((float)(2 * i) * (-9.210340371976184f / 256.0f));
    const float ang = (float)s * dv;
    const float pe = (t & 1) ? cosf(ang) : sinf(ang);
    h[(size_t)m * 256 + t] = (bf16)(acc + pe);
}

// ---------------------------------------------------------------------------
// LayerNorm with bf16 residual add: h = LN(h + add)*s + b. grid 8192.
// ---------------------------------------------------------------------------
__global__ __launch_bounds__(256) void ln_kernel(
    bf16* __restrict__ h, const bf16* __restrict__ add,
    const bf16* __restrict__ s, const bf16* __restrict__ b) {
    const int m = blockIdx.x, t = threadIdx.x;
    float x = (float)h[(size_t)m * 256 + t] + (float)add[(size_t)m * 256 + t];
    float s1 = x, s2 = x * x;
#pragma unroll
    for (int msk = 1; msk < 64; msk <<= 1) {
        s1 += __shfl_xor(s1, msk, 64);
        s2 += __shfl_xor(s2, msk, 64);
    }
    __shared__ float w1[4], w2[4];
    if ((t & 63) == 0) { w1[t >> 6] = s1; w2[t >> 6] = s2; }
    __syncthreads();
    s1 = w1[0] + w1[1] + w1[2] + w1[3];
    s2 = w2[0] + w2[1] + w2[2] + w2[3];
    const float mean = s1 * (1.0f / 256.0f);
    const float var = fmaxf(s2 * (1.0f / 256.0f) - mean * mean, 0.0f);
    const float inv = rsqrtf(var + 1e-5f);
    h[(size_t)m * 256 + t] = (bf16)((x - mean) * inv * (float)s[t] + (float)b[t]);
}

// ---------------------------------------------------------------------------
// Gate: logits -> top-2 (expert ids, softmax-of-top2 weights), expert counts,
// full-softmax aux partials. grid 256 x 256 threads (32 tokens/block).
// ---------------------------------------------------------------------------
__global__ __launch_bounds__(256) void gate_kernel(
    const bf16* __restrict__ h, const bf16* __restrict__ gw,
    const bf16* __restrict__ gb, int* __restrict__ top_e,
    float* __restrict__ top_w, int* __restrict__ cnt,
    float* __restrict__ aux_sums) {
    __shared__ float lg[32][8];
    __shared__ float psum[8];
    const int tid = threadIdx.x;
    const int tok = blockIdx.x * 32 + (tid >> 3), e = tid & 7;
    float acc = 0.0f;
    for (int k = 0; k < 256; k += 8) {
        bf16x8 hv = *(const bf16x8*)&h[(size_t)tok * 256 + k];
        bf16x8 wv = *(const bf16x8*)&gw[e * 256 + k];
#pragma unroll
        for (int j = 0; j < 8; j++) acc += (float)hv[j] * (float)wv[j];
    }
    lg[tid >> 3][e] = acc + (float)gb[e];
    if (tid < 8) psum[tid] = 0.0f;
    __syncthreads();
    if (tid < 32) {
        const int t2 = blockIdx.x * 32 + tid;
        float l[8];
#pragma unroll
        for (int j = 0; j < 8; j++) l[j] = lg[tid][j];
        int i0 = 0;
#pragma unroll
        for (int j = 1; j < 8; j++)
            if (l[j] > l[i0]) i0 = j;
        int i1 = -1;
#pragma unroll
        for (int j = 0; j < 8; j++)
            if (j != i0 && (i1 < 0 || l[j] > l[i1])) i1 = j;
        const float p0 = 1.0f / (1.0f + expf(l[i1] - l[i0]));
        top_e[t2] = i0;         top_w[t2] = p0;
        top_e[8192 + t2] = i1;  top_w[8192 + t2] = 1.0f - p0;
        atomicAdd(&cnt[i0], 1);
        atomicAdd(&cnt[8 + i1], 1);
        const float mx = l[i0];
        float se = 0.0f, pe[8];
#pragma unroll
        for (int j = 0; j < 8; j++) { pe[j] = expf(l[j] - mx); se += pe[j]; }
        const float inv = 1.0f / se;
#pragma unroll
        for (int j = 0; j < 8; j++) atomicAdd(&psum[j], pe[j] * inv);
    }
    __syncthreads();
    if (tid < 8) atomicAdd(&aux_sums[tid], psum[tid]);
}

// ---------------------------------------------------------------------------
// Build per-expert segments (padded to 128) + tile->expert map + pad fill.
// Single block, 256 threads.
// ---------------------------------------------------------------------------
__global__ void route_build_kernel(
    const int* __restrict__ cnt, int* __restrict__ seg_off,
    int* __restrict__ ntiles, int* __restrict__ tile_ex,
    int* __restrict__ list, float* __restrict__ lw) {
    const int tid = threadIdx.x;
    __shared__ int tot_s[2];
    if (tid == 0) {
        for (int slot = 0; slot < 2; slot++) {
            int o = 0;
            for (int e = 0; e < 8; e++) {
                seg_off[slot * 8 + e] = o;
                const int nt = (cnt[slot * 8 + e] + 127) >> 7;
                for (int t = 0; t < nt; t++) tile_ex[slot * 72 + (o >> 7) + t] = e;
                o += nt << 7;
            }
            ntiles[slot] = o >> 7;
            tot_s[slot] = o;
        }
    }
    __syncthreads();
    for (int slot = 0; slot < 2; slot++) {
        const int tot = tot_s[slot];
        for (int i = tid; i < tot; i += 256) {
            list[slot * 9216 + i] = 8192;
            lw[slot * 9216 + i] = 0.0f;
        }
    }
}

// Scatter tokens into their expert segments. grid 32 x 256.
__global__ __launch_bounds__(256) void scatter_kernel(
    const int* __restrict__ top_e, const float* __restrict__ top_w,
    const int* __restrict__ seg_off, int* __restrict__ pos,
    int* __restrict__ list, float* __restrict__ lw) {
    const int tok = blockIdx.x * 256 + threadIdx.x;
#pragma unroll
    for (int slot = 0; slot < 2; slot++) {
        const int e = top_e[slot * 8192 + tok];
        const int p = atomicAdd(&pos[slot * 8 + e], 1);
        const int idx = seg_off[slot * 8 + e] + p;
        list[slot * 9216 + idx] = tok;
        lw[slot * 9216 + idx] = top_w[slot * 8192 + tok];
    }
}

// ---------------------------------------------------------------------------
// Fused attention, one (b,h) x 32-query tile per block. grid (16,128).
// R3: V^T staged in LDS (two 256-key halves), lane-interleaved softmax cols
// (2-way bank aliasing = free), exp cached in LDS (one expf per element).
// ---------------------------------------------------------------------------
__global__ __launch_bounds__(256) void attn_kernel(
    const bf16* __restrict__ qkv, bf16* __restrict__ aout) {
    __shared__ alignas(16) bf16 P[32][520];
    __shared__ alignas(16) bf16 Vt[32][264];
    const int s0 = blockIdx.x * 32;
    const int b = blockIdx.y >> 3, hh = blockIdx.y & 7;
    const int tid = threadIdx.x, wave = tid >> 6, lane = tid & 63;
    const int frow = lane & 15, fquad = lane >> 4;
    const size_t base = (size_t)b * 512;
    const float scale = 0.17677669529663687f;  // 1/sqrt(32)

    // ---- S = Q K^T * scale ----
    bf16x8 qf[2];
#pragma unroll
    for (int mt = 0; mt < 2; mt++)
        qf[mt] = *(const bf16x8*)&qkv[(base + s0 + mt * 16 + frow) * 768 + hh * 32 + fquad * 8];
#pragma unroll
    for (int k8 = 0; k8 < 8; k8++) {
        const int key0 = (wave * 8 + k8) * 16;
        bf16x8 kf = *(const bf16x8*)&qkv[(base + key0 + frow) * 768 + 256 + hh * 32 + fquad * 8];
#pragma unroll
        for (int mt = 0; mt < 2; mt++) {
            f32x4 c = {};
            c = __builtin_amdgcn_mfma_f32_16x16x32_bf16(qf[mt], kf, c, 0, 0, 0);
#pragma unroll
            for (int r = 0; r < 4; r++)
                P[mt * 16 + fquad * 4 + r][key0 + frow] = (bf16)(c[r] * scale);
        }
    }
    __syncthreads();

    // ---- softmax: 8 threads/row, lane-interleaved cols, exp cached ----
    {
        const int row = tid >> 3, c0 = tid & 7;
        float mx = -1e30f;
        for (int j = 0; j < 64; j++) mx = fmaxf(mx, (float)P[row][c0 + 8 * j]);
#pragma unroll
        for (int msk = 1; msk < 8; msk <<= 1) mx = fmaxf(mx, __shfl_xor(mx, msk, 64));
        float se = 0.0f;
        for (int j = 0; j < 64; j++) {
            const float e_ = expf((float)P[row][c0 + 8 * j] - mx);
            se += e_;
            P[row][c0 + 8 * j] = (bf16)e_;
        }
#pragma unroll
        for (int msk = 1; msk < 8; msk <<= 1) se += __shfl_xor(se, msk, 64);
        const float inv = 1.0f / se;
        for (int j = 0; j < 64; j++)
            P[row][c0 + 8 * j] = (bf16)((float)P[row][c0 + 8 * j] * inv);
    }
    __syncthreads();

    // ---- O = P V via LDS-staged V^T, two 256-key halves ----
    {
        const int mt = wave >> 1, nt = wave & 1;
        f32x4 o = {};
#pragma unroll
        for (int half = 0; half < 2; half++) {
            if (half) __syncthreads();  // all reads of previous Vt half done
            {
                const int k = half * 256 + tid;
                const bf16* vr = &qkv[(base + k) * 768 + 512 + hh * 32];
                bf16x8 a0 = *(const bf16x8*)vr;
                bf16x8 a1 = *(const bf16x8*)(vr + 8);
                bf16x8 a2 = *(const bf16x8*)(vr + 16);
                bf16x8 a3 = *(const bf16x8*)(vr + 24);
#pragma unroll
                for (int c = 0; c < 8; c++) {
                    Vt[c][tid]      = a0[c];
                    Vt[c + 8][tid]  = a1[c];
                    Vt[c + 16][tid] = a2[c];
                    Vt[c + 24][tid] = a3[c];
                }
            }
            __syncthreads();
#pragma unroll
            for (int ks = 0; ks < 8; ks++) {
                bf16x8 pf = *(const bf16x8*)&P[mt * 16 + frow][half * 256 + ks * 32 + fquad * 8];
                bf16x8 vf = *(const bf16x8*)&Vt[nt * 16 + frow][ks * 32 + fquad * 8];
                o = __builtin_amdgcn_mfma_f32_16x16x32_bf16(pf, vf, o, 0, 0, 0);
            }
        }
#pragma unroll
        for (int r = 0; r < 4; r++)
            aout[(base + s0 + mt * 16 + fquad * 4 + r) * 256 + hh * 32 + nt * 16 + frow] = (bf16)o[r];
    }
}

// ---------------------------------------------------------------------------
// Pooled attention (last-token query) + projection + heads (as R2).
// ---------------------------------------------------------------------------
__global__ __launch_bounds__(256) void pooled_attn_kernel(
    const bf16* __restrict__ qkv, bf16* __restrict__ pa) {
    const int wid = blockIdx.x * 4 + (threadIdx.x >> 6);
    const int lane = threadIdx.x & 63;
    const int b = wid >> 3, hh = wid & 7;
    const size_t base = (size_t)b * 512;
    const float scale = 0.17677669529663687f;
    float q[32];
#pragma unroll
    for (int d = 0; d < 32; d++) q[d] = (float)qkv[(base + 511) * 768 + hh * 32 + d];
    float sc[8];
    float mx = -1e30f;
#pragma unroll
    for (int j = 0; j < 8; j++) {
        const int key = lane + j * 64;
        const bf16* kr = &qkv[(base + key) * 768 + 256 + hh * 32];
        float s = 0.0f;
#pragma unroll
        for (int d = 0; d < 32; d++) s += q[d] * (float)kr[d];
        s *= scale;
        sc[j] = s;
        mx = fmaxf(mx, s);
    }
#pragma unroll
    for (int m = 1; m < 64; m <<= 1) mx = fmaxf(mx, __shfl_xor(mx, m, 64));
    float se = 0.0f;
#pragma unroll
    for (int j = 0; j < 8; j++) { sc[j] = expf(sc[j] - mx); se += sc[j]; }
#pragma unroll
    for (int m = 1; m < 64; m <<= 1) se += __shfl_xor(se, m, 64);
    float o[32] = {};
#pragma unroll
    for (int j = 0; j < 8; j++) {
        const int key = lane + j * 64;
        const bf16* vr = &qkv[(base + key) * 768 + 512 + hh * 32];
#pragma unroll
        for (int d = 0; d < 32; d++) o[d] += sc[j] * (float)vr[d];
    }
#pragma unroll
    for (int d = 0; d < 32; d++) {
#pragma unroll
        for (int m = 1; m < 64; m <<= 1) o[d] += __shfl_xor(o[d], m, 64);
    }
    if (lane == 0) {
        const float inv = 1.0f / se;
        for (int d = 0; d < 32; d++) pa[b * 256 + hh * 32 + d] = (bf16)(o[d] * inv);
    }
}

__global__ __launch_bounds__(256) void pooled_proj_kernel(
    const bf16* __restrict__ pa, const bf16* __restrict__ w,
    const bf16* __restrict__ bias, bf16* __restrict__ pooled) {
    const int b = blockIdx.x, t = threadIdx.x;
    __shared__ float xs[256];
    xs[t] = (float)pa[b * 256 + t];
    __syncthreads();
    float acc = (float)bias[t];
    for (int k = 0; k < 256; k++) acc += xs[k] * (float)w[t * 256 + k];
    pooled[b * 256 + t] = (bf16)acc;
}

__global__ __launch_bounds__(256) void heads_kernel(
    const bf16* __restrict__ pooled,
    const bf16* __restrict__ aw1, const bf16* __restrict__ ab1,
    const bf16* __restrict__ aln1s, const bf16* __restrict__ aln1b,
    const bf16* __restrict__ aw2, const bf16* __restrict__ ab2,
    const bf16* __restrict__ aln2s, const bf16* __restrict__ aln2b,
    const bf16* __restrict__ aw3, const bf16* __restrict__ ab3,
    const bf16* __restrict__ pw1, const bf16* __restrict__ pb1,
    const bf16* __restrict__ pln1s, const bf16* __restrict__ pln1b,
    const bf16* __restrict__ pw2, const bf16* __restrict__ pb2,
    const bf16* __restrict__ pln2s, const bf16* __restrict__ pln2b,
    const bf16* __restrict__ pw3, const bf16* __restrict__ pb3,
    float* __restrict__ out) {
    const int b = blockIdx.x, t = threadIdx.x;
    __shared__ float pool[256], buf[256], buf2[256], r1[256], r2[256];
    pool[t] = (float)pooled[b * 256 + t];
    __syncthreads();

    auto block_ln = [&](float* v, int W, const bf16* ls, const bf16* lb) {
        const float val = (t < W) ? v[t] : 0.0f;
        r1[t] = val;
        r2[t] = val * val;
        __syncthreads();
        for (int off = 128; off > 0; off >>= 1) {
            if (t < off) { r1[t] += r1[t + off]; r2[t] += r2[t + off]; }
            __syncthreads();
        }
        const float mean = r1[0] / (float)W;
        const float var = fmaxf(r2[0] / (float)W - mean * mean, 0.0f);
        const float inv = rsqrtf(var + 1e-5f);
        __syncthreads();
        if (t < W) v[t] = (val - mean) * inv * (float)ls[t] + (float)lb[t];
        __syncthreads();
    };

    float a;
    if (t < 128) {
        a = (float)ab1[t];
        for (int k = 0; k < 256; k++) a += pool[k] * (float)aw1[t * 256 + k];
        buf[t] = gelu_exact(a);
    }
    __syncthreads();
    block_ln(buf, 128, aln1s, aln1b);
    if (t < 64) {
        a = (float)ab2[t];
        for (int k = 0; k < 128; k++) a += buf[k] * (float)aw2[t * 128 + k];
        buf2[t] = gelu_exact(a);
    }
    __syncthreads();
    block_ln(buf2, 64, aln2s, aln2b);
    if (t < 3) {
        a = (float)ab3[t];
        for (int k = 0; k < 64; k++) a += buf2[k] * (float)aw3[t * 64 + k];
        out[b * 3 + t] = a;
    }

    a = (float)pb1[t];
    for (int k = 0; k < 256; k++) a += pool[k] * (float)pw1[t * 256 + k];
    buf[t] = a;
    __syncthreads();
    block_ln(buf, 256, pln1s, pln1b);
    buf[t] = gelu_exact(buf[t]);
    __syncthreads();
    if (t < 128) {
        a = (float)pb2[t];
        for (int k = 0; k < 256; k++) a += buf[k] * (float)pw2[t * 256 + k];
        buf2[t] = a;
    }
    __syncthreads();
    block_ln(buf2, 128, pln2s, pln2b);
    if (t < 128) buf2[t] = gelu_exact(buf2[t]);
    __syncthreads();
    if (t == 0) {
        a = (float)pb3[0];
        for (int k = 0; k < 128; k++) a += buf2[k] * (float)pw3[k];
        out[48 + b] = a;
    }
}

__global__ void aux_kernel(const float* __restrict__ sums, float* __restrict__ out) {
    if (threadIdx.x == 0 && blockIdx.x == 0) {
        float tot = 0.0f;
        for (int l = 0; l < 6; l++)
            for (int e = 0; e < 8; e++) {
                const float mn = sums[l * 8 + e] * (1.0f / 8192.0f);
                tot += 8.0f * mn * mn;
            }
        out[64] = tot;
    }
}

// ---------------------------------------------------------------------------
extern "C" void kernel_launch(void* const* d_in, const int* in_sizes, int n_in,
                              void* d_out, int out_size, void* d_ws, size_t ws_size,
                              hipStream_t stream) {
    char* ws = (char*)d_ws;
    bf16*  h     = (bf16*)(ws);                         // 8193x256
    bf16*  moe   = (bf16*)(ws + 4456448);               // 8193x256
    char*  ctrl  = ws + 8912896;
    float* auxs   = (float*)(ctrl + 0);                 // 48 f32
    int*   cnt    = (int*)(ctrl + 192);                 // [2][8]
    int*   pos    = (int*)(ctrl + 256);                 // [2][8]
    int*   flag   = (int*)(ctrl + 384);
    int*   segoff = (int*)(ctrl + 448);                 // [2][8]
    int*   ntiles = (int*)(ctrl + 512);                 // [2]
    int*   tileex = (int*)(ctrl + 576);                 // [2][72]
    float* ostage = (float*)(ctrl + 1280);              // 65 f32
    int*   top_e  = (int*)(ctrl + 4096);                // [2][8192]
    float* top_w  = (float*)(ctrl + 69632);             // [2][8192]
    int*   list   = (int*)(ctrl + 135168);              // [2][9216]
    float* lw     = (float*)(ctrl + 208896);            // [2][9216]
    char*  big   = ws + 9961472;
    bf16*  qkv   = (bf16*)(big);                        // 8192x768
    bf16*  aoutb = (bf16*)(big + 12582912);             // 8192x256
    bf16*  projo = (bf16*)(big);                        // reuse (qkv dead)
    bf16*  hid   = (bf16*)(big);                        // 9216x1024 (reuse all)
    bf16*  pattn  = (bf16*)(ws + 29360128);
    bf16*  pooled = (bf16*)(ws + 29360128 + 8192);
    bf16*  cvbase = (bf16*)(ws + 29376512);             // ~10.1 MB

    InTab tab;
    unsigned off = 0;
    bf16* cv[NIN];
    for (int i = 0; i < NIN; i++) {
        tab.src[i] = d_in[i];
        tab.off[i] = off;
        tab.n[i] = (unsigned)in_sizes[i];
        cv[i] = cvbase + off;
        off += ((unsigned)in_sizes[i] + 7u) & ~7u;
    }

    const bf16 *x = cv[0], *in_w = cv[1], *in_b = cv[2], *qkv_w = cv[3], *qkv_b = cv[4],
               *out_w = cv[5], *out_b = cv[6], *gate_w = cv[7], *gate_b = cv[8],
               *e_w1 = cv[9], *e_b1 = cv[10], *e_w2 = cv[11], *e_b2 = cv[12],
               *ln1_s = cv[13], *ln1_b = cv[14], *ln2_s = cv[15], *ln2_b = cv[16],
               *pqkv_w = cv[17], *pqkv_b = cv[18], *pout_w = cv[19], *pout_b = cv[20],
               *a_w1 = cv[21], *a_b1 = cv[22], *a_ln1s = cv[23], *a_ln1b = cv[24],
               *a_w2 = cv[25], *a_b2 = cv[26], *a_ln2s = cv[27], *a_ln2b = cv[28],
               *a_w3 = cv[29], *a_b3 = cv[30],
               *pr_w1 = cv[31], *pr_b1 = cv[32], *pr_ln1s = cv[33], *pr_ln1b = cv[34],
               *pr_w2 = cv[35], *pr_b2 = cv[36], *pr_ln2s = cv[37], *pr_ln2b = cv[38],
               *pr_w3 = cv[39], *pr_b3 = cv[40];

    sniff_kernel<<<1, 256, 0, stream>>>((const unsigned*)d_in[0], flag);
    convert_kernel<<<dim3(2048, NIN), 256, 0, stream>>>(tab, cvbase, flag);

    hipMemsetAsync(auxs, 0, 320, stream);   // auxs + cnt + pos
    input_proj_kernel<<<8192, 256, 0, stream>>>(x, in_w, in_b, h);

    for (int l = 0; l < 6; l++) {
        gemm_bt<128, 128, 64, 64><<<dim3(64, 6), 256, 0, stream>>>(
            h, qkv_w, qkv_b, qkv, 8192, 768, 256);
        attn_kernel<<<dim3(16, 128), 256, 0, stream>>>(qkv, aoutb);
        gemm_bt<128, 64, 32, 64><<<dim3(64, 4), 256, 0, stream>>>(
            aoutb, out_w, out_b, projo, 8192, 256, 256);
        ln_kernel<<<8192, 256, 0, stream>>>(h, projo, ln1_s, ln1_b);

        // routing
        gate_kernel<<<256, 256, 0, stream>>>(h, gate_w, gate_b,
                                             top_e, top_w, cnt + l * 0 /*reset below*/,
                                             auxs + l * 8);
        route_build_kernel<<<1, 256, 0, stream>>>(cnt, segoff, ntiles, tileex, list, lw);
        scatter_kernel<<<32, 256, 0, stream>>>(top_e, top_w, segoff, pos, list, lw);

        // top-2 expert FFN (slot 0 = top-1 covers every token: write; slot 1: accumulate)
        for (int slot = 0; slot < 2; slot++) {
            gemm_moe<128, 128, 64, 64, 1><<<dim3(71, 8), 256, 0, stream>>>(
                h, e_w1, e_b1, hid, 1024, 256,
                list + slot * 9216, lw + slot * 9216, tileex + slot * 72, ntiles + slot);
            if (slot == 0)
                gemm_moe<128, 64, 32, 64, 2><<<dim3(71, 4), 256, 0, stream>>>(
                    hid, e_w2, e_b2, moe, 256, 1024,
                    list, lw, tileex, ntiles);
            else
                gemm_moe<128, 64, 32, 64, 3><<<dim3(71, 4), 256, 0, stream>>>(
                    hid, e_w2, e_b2, moe, 256, 1024,
                    list + 9216, lw + 9216, tileex + 72, ntiles + 1);
        }
        ln_kernel<<<8192, 256, 0, stream>>>(h, moe, ln2_s, ln2_b);

        // reset routing counters for next layer
        hipMemsetAsync(cnt, 0, 128, stream);  // cnt + pos
    }

    gemm_bt<128, 128, 64, 64><<<dim3(64, 6), 256, 0, stream>>>(
        h, pqkv_w, pqkv_b, qkv, 8192, 768, 256);
    pooled_attn_kernel<<<32, 256, 0, stream>>>(qkv, pattn);
    pooled_proj_kernel<<<16, 256, 0, stream>>>(pattn, pout_w, pout_b, pooled);

    heads_kernel<<<16, 256, 0, stream>>>(
        pooled,
        a_w1, a_b1, a_ln1s, a_ln1b, a_w2, a_b2, a_ln2s, a_ln2b, a_w3, a_b3,
        pr_w1, pr_b1, pr_ln1s, pr_ln1b, pr_w2, pr_b2, pr_ln2s, pr_ln2b, pr_w3, pr_b3,
        ostage);
    aux_kernel<<<1, 64, 0, stream>>>(auxs, ostage);
    out_convert_kernel<<<1, 128, 0, stream>>>(ostage, d_out, flag);
}

// Round 4
// 1484.308 us; speedup vs baseline: 1.8966x; 1.8966x over previous
//
#include <hip/hip_runtime.h>
#include <hip/hip_bf16.h>
#include <math.h>

// ---------------------------------------------------------------------------
// MoE trading transformer forward, MI355X/gfx950.
// B=16 S=512 F_IN=46 D=256 H=8 (dh=32) L=6 E=8 DFF=1024 OUT=3.
// R4: routing rebuilt as atomic-free counting sort (R3's per-token global
// atomics to one cache line serialized at the LLC: gate 133us -> ~8us).
//
// Workspace (~39.9 MB):
//   [0]      h    bf16 8193x256 (row 8192 = pad-token scratch)
//   [4.25M]  moe  bf16 8193x256
//   [8.5M]   ctrl (~282 KB): auxs|flag|ntiles|tile_ex|ostage|g_hist|boff|
//                            top_e|top_w|list|lw
//   [9.5M]   big: qkv bf16 8192x768 (12M) | aout (4M); reused: projo, hid
//   [28M]    pattn, pooled
//   [28.02M] cvbase: canonical bf16 copies of all 41 inputs (~10.1M)
// ---------------------------------------------------------------------------

typedef __bf16 bf16;
typedef __bf16 bf16x8 __attribute__((ext_vector_type(8)));
typedef float f32x4 __attribute__((ext_vector_type(4)));

#define NIN 41

struct InTab {
    const void* src[NIN];
    unsigned off[NIN];
    unsigned n[NIN];
};

__device__ __forceinline__ float gelu_exact(float x) {
    return 0.5f * x * (1.0f + erff(x * 0.70710678118654752f));
}

// ---------------------------------------------------------------------------
// Dtype sniffer (f32 vs bf16 storage). flag: 1=bf16, 0=f32.
// ---------------------------------------------------------------------------
__global__ void sniff_kernel(const unsigned* __restrict__ xw, int* __restrict__ flag) {
    __shared__ int cnt;
    if (threadIdx.x == 0) cnt = 0;
    __syncthreads();
    const unsigned w = xw[threadIdx.x];
    const unsigned ex = (w >> 7) & 0xFFu;
    if (ex >= 107u && ex <= 133u) atomicAdd(&cnt, 1);
    __syncthreads();
    if (threadIdx.x == 0) *flag = (cnt >= 192) ? 1 : 0;
}

__global__ __launch_bounds__(256) void convert_kernel(
    InTab tab, bf16* __restrict__ dst_base, const int* __restrict__ flag) {
    const int inp = blockIdx.y;
    const unsigned n = tab.n[inp];
    const unsigned i0 = (blockIdx.x * 256u + threadIdx.x) * 4u;
    if (i0 >= n) return;
    const int isbf = *flag;
    bf16* dst = dst_base + tab.off[inp];
    const unsigned end = (i0 + 4u > n) ? n : i0 + 4u;
    if (isbf) {
        const unsigned short* s = (const unsigned short*)tab.src[inp];
        for (unsigned i = i0; i < end; i++) ((unsigned short*)dst)[i] = s[i];
    } else {
        const float* s = (const float*)tab.src[inp];
        for (unsigned i = i0; i < end; i++) dst[i] = (bf16)s[i];
    }
}

__global__ void out_convert_kernel(const float* __restrict__ st, void* __restrict__ out,
                                   const int* __restrict__ flag) {
    const int i = threadIdx.x;
    if (i >= 65) return;
    if (*flag) ((bf16*)out)[i] = (bf16)st[i];
    else       ((float*)out)[i] = st[i];
}

// ---------------------------------------------------------------------------
// Dense MFMA GEMM:  C[M,N] = A[M,K] @ W[N,K]^T + bias[N]
// ---------------------------------------------------------------------------
template <int BM, int BN, int WM, int WN>
__global__ __launch_bounds__(256) void gemm_bt(
    const bf16* __restrict__ A, const bf16* __restrict__ W,
    const bf16* __restrict__ bias, bf16* __restrict__ C,
    int M, int N, int K) {
    constexpr int BK = 64;
    __shared__ alignas(16) bf16 As[BM][BK + 8];
    __shared__ alignas(16) bf16 Ws[BN][BK + 8];
    const int bm0 = blockIdx.x * BM, bn0 = blockIdx.y * BN;
    const int tid = threadIdx.x;
    const int wave = tid >> 6, lane = tid & 63;
    constexpr int WCOLS = BN / WN;
    const int wm0 = (wave / WCOLS) * WM, wn0 = (wave % WCOLS) * WN;
    constexpr int MT = WM / 16, NT = WN / 16;
    f32x4 acc[MT][NT] = {};
    const int lrow = tid >> 3, lcol = (tid & 7) * 8;
    const int frow = lane & 15, fquad = lane >> 4;

    for (int k0 = 0; k0 < K; k0 += BK) {
#pragma unroll
        for (int p = 0; p < BM / 32; p++)
            *(bf16x8*)&As[lrow + p * 32][lcol] =
                *(const bf16x8*)&A[(size_t)(bm0 + lrow + p * 32) * K + k0 + lcol];
#pragma unroll
        for (int p = 0; p < BN / 32; p++)
            *(bf16x8*)&Ws[lrow + p * 32][lcol] =
                *(const bf16x8*)&W[(size_t)(bn0 + lrow + p * 32) * K + k0 + lcol];
        __syncthreads();
#pragma unroll
        for (int ks = 0; ks < BK / 32; ks++) {
            bf16x8 af[MT], bfr[NT];
#pragma unroll
            for (int mt = 0; mt < MT; mt++)
                af[mt] = *(const bf16x8*)&As[wm0 + mt * 16 + frow][ks * 32 + fquad * 8];
#pragma unroll
            for (int nt = 0; nt < NT; nt++)
                bfr[nt] = *(const bf16x8*)&Ws[wn0 + nt * 16 + frow][ks * 32 + fquad * 8];
#pragma unroll
            for (int mt = 0; mt < MT; mt++)
#pragma unroll
                for (int nt = 0; nt < NT; nt++)
                    acc[mt][nt] = __builtin_amdgcn_mfma_f32_16x16x32_bf16(
                        af[mt], bfr[nt], acc[mt][nt], 0, 0, 0);
        }
        __syncthreads();
    }

#pragma unroll
    for (int mt = 0; mt < MT; mt++)
#pragma unroll
        for (int nt = 0; nt < NT; nt++) {
            const int gn = bn0 + wn0 + nt * 16 + frow;
            const float bv = (float)bias[gn];
#pragma unroll
            for (int r = 0; r < 4; r++) {
                const int gm = bm0 + wm0 + mt * 16 + fquad * 4 + r;
                C[(size_t)gm * N + gn] = (bf16)(acc[mt][nt][r] + bv);
            }
        }
}

// ---------------------------------------------------------------------------
// Routed MoE GEMM over a compacted token list.
// MODE 1: hid[i] = GELU(h[list[i]] @ w1_e^T + b1_e)      (N=1024,K=256)
// MODE 2: moe[list[i]]  = lw[i]*(hid[i] @ w2_e^T + b2_e) (N=256, K=1024)
// MODE 3: moe[list[i]] += lw[i]*(...)
// ---------------------------------------------------------------------------
template <int BM, int BN, int WM, int WN, int MODE>
__global__ __launch_bounds__(256) void gemm_moe(
    const bf16* __restrict__ A, const bf16* __restrict__ Wb,
    const bf16* __restrict__ biasb, bf16* __restrict__ C,
    int N, int K, const int* __restrict__ list, const float* __restrict__ lw,
    const int* __restrict__ tile_ex, const int* __restrict__ ntiles) {
    if ((int)blockIdx.x >= *ntiles) return;
    constexpr int BK = 64;
    __shared__ alignas(16) bf16 As[BM][BK + 8];
    __shared__ alignas(16) bf16 Ws[BN][BK + 8];
    const int e = tile_ex[blockIdx.x];
    const bf16* W = Wb + (size_t)e * N * K;
    const bf16* bias = biasb + e * N;
    const int bm0 = blockIdx.x * BM, bn0 = blockIdx.y * BN;
    const int tid = threadIdx.x;
    const int wave = tid >> 6, lane = tid & 63;
    constexpr int WCOLS = BN / WN;
    const int wm0 = (wave / WCOLS) * WM, wn0 = (wave % WCOLS) * WN;
    constexpr int MT = WM / 16, NT = WN / 16;
    f32x4 acc[MT][NT] = {};
    const int lrow = tid >> 3, lcol = (tid & 7) * 8;
    const int frow = lane & 15, fquad = lane >> 4;

    int arow[BM / 32];
#pragma unroll
    for (int p = 0; p < BM / 32; p++) {
        const int r = bm0 + lrow + p * 32;
        arow[p] = (MODE == 1) ? list[r] : r;
    }

    for (int k0 = 0; k0 < K; k0 += BK) {
#pragma unroll
        for (int p = 0; p < BM / 32; p++)
            *(bf16x8*)&As[lrow + p * 32][lcol] =
                *(const bf16x8*)&A[(size_t)arow[p] * K + k0 + lcol];
#pragma unroll
        for (int p = 0; p < BN / 32; p++)
            *(bf16x8*)&Ws[lrow + p * 32][lcol] =
                *(const bf16x8*)&W[(size_t)(bn0 + lrow + p * 32) * K + k0 + lcol];
        __syncthreads();
#pragma unroll
        for (int ks = 0; ks < BK / 32; ks++) {
            bf16x8 af[MT], bfr[NT];
#pragma unroll
            for (int mt = 0; mt < MT; mt++)
                af[mt] = *(const bf16x8*)&As[wm0 + mt * 16 + frow][ks * 32 + fquad * 8];
#pragma unroll
            for (int nt = 0; nt < NT; nt++)
                bfr[nt] = *(const bf16x8*)&Ws[wn0 + nt * 16 + frow][ks * 32 + fquad * 8];
#pragma unroll
            for (int mt = 0; mt < MT; mt++)
#pragma unroll
                for (int nt = 0; nt < NT; nt++)
                    acc[mt][nt] = __builtin_amdgcn_mfma_f32_16x16x32_bf16(
                        af[mt], bfr[nt], acc[mt][nt], 0, 0, 0);
        }
        __syncthreads();
    }

#pragma unroll
    for (int mt = 0; mt < MT; mt++)
#pragma unroll
        for (int nt = 0; nt < NT; nt++) {
            const int gn = bn0 + wn0 + nt * 16 + frow;
            const float bv = (float)bias[gn];
#pragma unroll
            for (int r = 0; r < 4; r++) {
                const int gm = bm0 + wm0 + mt * 16 + fquad * 4 + r;
                const float v = acc[mt][nt][r] + bv;
                if (MODE == 1) {
                    C[(size_t)gm * N + gn] = (bf16)gelu_exact(v);
                } else {
                    const int token = list[gm];
                    const float s = lw[gm];
                    bf16* dst = &C[(size_t)token * 256 + gn];
                    if (MODE == 2) *dst = (bf16)(s * v);
                    else           *dst = (bf16)((float)*dst + s * v);
                }
            }
        }
}

// ---------------------------------------------------------------------------
// Input projection + positional encoding. grid 8192, block 256.
// ---------------------------------------------------------------------------
__global__ __launch_bounds__(256) void input_proj_kernel(
    const bf16* __restrict__ x, const bf16* __restrict__ w,
    const bf16* __restrict__ b, bf16* __restrict__ h) {
    const int m = blockIdx.x, t = threadIdx.x;
    __shared__ float xs[46];
    if (t < 46) xs[t] = (float)x[m * 46 + t];
    __syncthreads();
    float acc = (float)b[t];
#pragma unroll
    for (int k = 0; k < 46; k++) acc += xs[k] * (float)w[t * 46 + k];
    const int s = m & 511;
    const int i = t >> 1;
    const float dv = expf((float)(2 * i) * (-9.210340371976184f / 256.0f));
    const float ang = (float)s * dv;
    const float pe = (t & 1) ? cosf(ang) : sinf(ang);
    h[(size_t)m * 256 + t] = (bf16)(acc + pe);
}

// ---------------------------------------------------------------------------
// LayerNorm with bf16 residual add: h = LN(h + add)*s + b. grid 8192.
// ---------------------------------------------------------------------------
__global__ __launch_bounds__(256) void ln_kernel(
    bf16* __restrict__ h, const bf16* __restrict__ add,
    const bf16* __restrict__ s, const bf16* __restrict__ b) {
    const int m = blockIdx.x, t = threadIdx.x;
    float x = (float)h[(size_t)m * 256 + t] + (float)add[(size_t)m * 256 + t];
    float s1 = x, s2 = x * x;
#pragma unroll
    for (int msk = 1; msk < 64; msk <<= 1) {
        s1 += __shfl_xor(s1, msk, 64);
        s2 += __shfl_xor(s2, msk, 64);
    }
    __shared__ float w1[4], w2[4];
    if ((t & 63) == 0) { w1[t >> 6] = s1; w2[t >> 6] = s2; }
    __syncthreads();
    s1 = w1[0] + w1[1] + w1[2] + w1[3];
    s2 = w2[0] + w2[1] + w2[2] + w2[3];
    const float mean = s1 * (1.0f / 256.0f);
    const float var = fmaxf(s2 * (1.0f / 256.0f) - mean * mean, 0.0f);
    const float inv = rsqrtf(var + 1e-5f);
    h[(size_t)m * 256 + t] = (bf16)((x - mean) * inv * (float)s[t] + (float)b[t]);
}

// ---------------------------------------------------------------------------
// R4 gate: grid 64 x 256 threads, 128 tokens/block. Logits -> top-2 ->
// per-block LDS histogram -> plain store. Aux via per-block reduction +
// 8 uncontended global atomicAdds. NO per-token global atomics.
// ---------------------------------------------------------------------------
__global__ __launch_bounds__(256) void gate_kernel(
    const bf16* __restrict__ h, const bf16* __restrict__ gw,
    const bf16* __restrict__ gb, int* __restrict__ top_e,
    float* __restrict__ top_w, int* __restrict__ g_hist,
    float* __restrict__ aux_sums) {
    __shared__ float lg[128][9];
    __shared__ float mxs[128], invs[128];
    __shared__ int hist[16];
    const int tid = threadIdx.x;
    if (tid < 16) hist[tid] = 0;
    const int e = tid & 7;
#pragma unroll
    for (int pass = 0; pass < 4; pass++) {
        const int tl = pass * 32 + (tid >> 3);
        const int tok = blockIdx.x * 128 + tl;
        float acc = 0.0f;
        for (int k = 0; k < 256; k += 8) {
            bf16x8 hv = *(const bf16x8*)&h[(size_t)tok * 256 + k];
            bf16x8 wv = *(const bf16x8*)&gw[e * 256 + k];
#pragma unroll
            for (int j = 0; j < 8; j++) acc += (float)hv[j] * (float)wv[j];
        }
        lg[tl][e] = acc + (float)gb[e];
    }
    __syncthreads();
    if (tid < 128) {
        const int tok = blockIdx.x * 128 + tid;
        float l[8];
#pragma unroll
        for (int j = 0; j < 8; j++) l[j] = lg[tid][j];
        int i0 = 0;
#pragma unroll
        for (int j = 1; j < 8; j++)
            if (l[j] > l[i0]) i0 = j;
        int i1 = -1;
#pragma unroll
        for (int j = 0; j < 8; j++)
            if (j != i0 && (i1 < 0 || l[j] > l[i1])) i1 = j;
        const float p0 = 1.0f / (1.0f + expf(l[i1] - l[i0]));
        top_e[tok] = i0;         top_w[tok] = p0;
        top_e[8192 + tok] = i1;  top_w[8192 + tok] = 1.0f - p0;
        atomicAdd(&hist[i0], 1);
        atomicAdd(&hist[8 + i1], 1);
        const float mx = l[i0];
        float se = 0.0f;
#pragma unroll
        for (int j = 0; j < 8; j++) se += expf(l[j] - mx);
        mxs[tid] = mx;
        invs[tid] = 1.0f / se;
    }
    __syncthreads();
    if (tid < 8) {
        float s = 0.0f;
        for (int t = 0; t < 128; t++) s += expf(lg[t][tid] - mxs[t]) * invs[t];
        atomicAdd(&aux_sums[tid], s);
    }
    if (tid < 16) g_hist[blockIdx.x * 16 + tid] = hist[tid];
}

// ---------------------------------------------------------------------------
// Build routing tables from per-block histograms. Single block, 256 threads.
// Outputs: boff[64][16] (per gate-block write cursors), ntiles[2],
// tile_ex[2][72], pad-fill of list/lw tails. seg index = slot*8 + e.
// ---------------------------------------------------------------------------
__global__ void route_build_kernel(
    const int* __restrict__ g_hist, int* __restrict__ boff,
    int* __restrict__ ntiles, int* __restrict__ tile_ex,
    int* __restrict__ list, float* __restrict__ lw) {
    const int tid = threadIdx.x;
    __shared__ int s_pre[64][16];
    __shared__ int s_cnt[16];
    __shared__ int s_off[16];
    if (tid < 16) {
        int run = 0;
        for (int b = 0; b < 64; b++) {
            s_pre[b][tid] = run;
            run += g_hist[b * 16 + tid];
        }
        s_cnt[tid] = run;
    }
    __syncthreads();
    if (tid < 2) {
        const int slot = tid;
        int o = 0;
        for (int e2 = 0; e2 < 8; e2++) {
            s_off[slot * 8 + e2] = o;
            const int nt = (s_cnt[slot * 8 + e2] + 127) >> 7;
            for (int t = 0; t < nt; t++) tile_ex[slot * 72 + (o >> 7) + t] = e2;
            o += nt << 7;
        }
        ntiles[slot] = o >> 7;
    }
    __syncthreads();
    if (tid < 16) {
        for (int b = 0; b < 64; b++)
            boff[b * 16 + tid] = s_off[tid] + s_pre[b][tid];
    }
    // pad fill: each segment's tail [off+cnt, off+ntile*128), pad < 128
    for (int idx = tid; idx < 16 * 128; idx += 256) {
        const int seg = idx >> 7, i = idx & 127;
        const int slot = seg >> 3;
        const int start = s_off[seg] + s_cnt[seg];
        const int end = s_off[seg] + ((s_cnt[seg] + 127) & ~127);
        const int p = start + i;
        if (p < end) {
            list[slot * 9216 + p] = 8192;
            lw[slot * 9216 + p] = 0.0f;
        }
    }
}

// Scatter tokens into expert segments. grid 64 x 256. LDS atomics only
// (within-segment order is irrelevant: entries carry token id + weight).
__global__ __launch_bounds__(256) void scatter_kernel(
    const int* __restrict__ top_e, const float* __restrict__ top_w,
    const int* __restrict__ boff, int* __restrict__ list,
    float* __restrict__ lw) {
    __shared__ int pos[16];
    const int tid = threadIdx.x;
    if (tid < 16) pos[tid] = boff[blockIdx.x * 16 + tid];
    __syncthreads();
    if (tid < 128) {
        const int tok = blockIdx.x * 128 + tid;
#pragma unroll
        for (int slot = 0; slot < 2; slot++) {
            const int e = top_e[slot * 8192 + tok];
            const float w = top_w[slot * 8192 + tok];
            const int idx = atomicAdd(&pos[slot * 8 + e], 1);
            list[slot * 9216 + idx] = tok;
            lw[slot * 9216 + idx] = w;
        }
    }
}

// ---------------------------------------------------------------------------
// Fused attention, one (b,h) x 32-query tile per block. grid (16,128).
// ---------------------------------------------------------------------------
__global__ __launch_bounds__(256) void attn_kernel(
    const bf16* __restrict__ qkv, bf16* __restrict__ aout) {
    __shared__ alignas(16) bf16 P[32][520];
    __shared__ alignas(16) bf16 Vt[32][264];
    const int s0 = blockIdx.x * 32;
    const int b = blockIdx.y >> 3, hh = blockIdx.y & 7;
    const int tid = threadIdx.x, wave = tid >> 6, lane = tid & 63;
    const int frow = lane & 15, fquad = lane >> 4;
    const size_t base = (size_t)b * 512;
    const float scale = 0.17677669529663687f;  // 1/sqrt(32)

    bf16x8 qf[2];
#pragma unroll
    for (int mt = 0; mt < 2; mt++)
        qf[mt] = *(const bf16x8*)&qkv[(base + s0 + mt * 16 + frow) * 768 + hh * 32 + fquad * 8];
#pragma unroll
    for (int k8 = 0; k8 < 8; k8++) {
        const int key0 = (wave * 8 + k8) * 16;
        bf16x8 kf = *(const bf16x8*)&qkv[(base + key0 + frow) * 768 + 256 + hh * 32 + fquad * 8];
#pragma unroll
        for (int mt = 0; mt < 2; mt++) {
            f32x4 c = {};
            c = __builtin_amdgcn_mfma_f32_16x16x32_bf16(qf[mt], kf, c, 0, 0, 0);
#pragma unroll
            for (int r = 0; r < 4; r++)
                P[mt * 16 + fquad * 4 + r][key0 + frow] = (bf16)(c[r] * scale);
        }
    }
    __syncthreads();

    {   // softmax: 8 threads/row, lane-interleaved cols, exp cached
        const int row = tid >> 3, c0 = tid & 7;
        float mx = -1e30f;
        for (int j = 0; j < 64; j++) mx = fmaxf(mx, (float)P[row][c0 + 8 * j]);
#pragma unroll
        for (int msk = 1; msk < 8; msk <<= 1) mx = fmaxf(mx, __shfl_xor(mx, msk, 64));
        float se = 0.0f;
        for (int j = 0; j < 64; j++) {
            const float e_ = expf((float)P[row][c0 + 8 * j] - mx);
            se += e_;
            P[row][c0 + 8 * j] = (bf16)e_;
        }
#pragma unroll
        for (int msk = 1; msk < 8; msk <<= 1) se += __shfl_xor(se, msk, 64);
        const float inv = 1.0f / se;
        for (int j = 0; j < 64; j++)
            P[row][c0 + 8 * j] = (bf16)((float)P[row][c0 + 8 * j] * inv);
    }
    __syncthreads();

    {   // O = P V via LDS-staged V^T, two 256-key halves
        const int mt = wave >> 1, nt = wave & 1;
        f32x4 o = {};
#pragma unroll
        for (int half = 0; half < 2; half++) {
            if (half) __syncthreads();
            {
                const int k = half * 256 + tid;
                const bf16* vr = &qkv[(base + k) * 768 + 512 + hh * 32];
                bf16x8 a0 = *(const bf16x8*)vr;
                bf16x8 a1 = *(const bf16x8*)(vr + 8);
                bf16x8 a2 = *(const bf16x8*)(vr + 16);
                bf16x8 a3 = *(const bf16x8*)(vr + 24);
#pragma unroll
                for (int c = 0; c < 8; c++) {
                    Vt[c][tid]      = a0[c];
                    Vt[c + 8][tid]  = a1[c];
                    Vt[c + 16][tid] = a2[c];
                    Vt[c + 24][tid] = a3[c];
                }
            }
            __syncthreads();
#pragma unroll
            for (int ks = 0; ks < 8; ks++) {
                bf16x8 pf = *(const bf16x8*)&P[mt * 16 + frow][half * 256 + ks * 32 + fquad * 8];
                bf16x8 vf = *(const bf16x8*)&Vt[nt * 16 + frow][ks * 32 + fquad * 8];
                o = __builtin_amdgcn_mfma_f32_16x16x32_bf16(pf, vf, o, 0, 0, 0);
            }
        }
#pragma unroll
        for (int r = 0; r < 4; r++)
            aout[(base + s0 + mt * 16 + fquad * 4 + r) * 256 + hh * 32 + nt * 16 + frow] = (bf16)o[r];
    }
}

// ---------------------------------------------------------------------------
// Pooled attention + projection + heads.
// ---------------------------------------------------------------------------
__global__ __launch_bounds__(256) void pooled_attn_kernel(
    const bf16* __restrict__ qkv, bf16* __restrict__ pa) {
    const int wid = blockIdx.x * 4 + (threadIdx.x >> 6);
    const int lane = threadIdx.x & 63;
    const int b = wid >> 3, hh = wid & 7;
    const size_t base = (size_t)b * 512;
    const float scale = 0.17677669529663687f;
    float q[32];
#pragma unroll
    for (int d = 0; d < 32; d++) q[d] = (float)qkv[(base + 511) * 768 + hh * 32 + d];
    float sc[8];
    float mx = -1e30f;
#pragma unroll
    for (int j = 0; j < 8; j++) {
        const int key = lane + j * 64;
        const bf16* kr = &qkv[(base + key) * 768 + 256 + hh * 32];
        float s = 0.0f;
#pragma unroll
        for (int d = 0; d < 32; d++) s += q[d] * (float)kr[d];
        s *= scale;
        sc[j] = s;
        mx = fmaxf(mx, s);
    }
#pragma unroll
    for (int m = 1; m < 64; m <<= 1) mx = fmaxf(mx, __shfl_xor(mx, m, 64));
    float se = 0.0f;
#pragma unroll
    for (int j = 0; j < 8; j++) { sc[j] = expf(sc[j] - mx); se += sc[j]; }
#pragma unroll
    for (int m = 1; m < 64; m <<= 1) se += __shfl_xor(se, m, 64);
    float o[32] = {};
#pragma unroll
    for (int j = 0; j < 8; j++) {
        const int key = lane + j * 64;
        const bf16* vr = &qkv[(base + key) * 768 + 512 + hh * 32];
#pragma unroll
        for (int d = 0; d < 32; d++) o[d] += sc[j] * (float)vr[d];
    }
#pragma unroll
    for (int d = 0; d < 32; d++) {
#pragma unroll
        for (int m = 1; m < 64; m <<= 1) o[d] += __shfl_xor(o[d], m, 64);
    }
    if (lane == 0) {
        const float inv = 1.0f / se;
        for (int d = 0; d < 32; d++) pa[b * 256 + hh * 32 + d] = (bf16)(o[d] * inv);
    }
}

__global__ __launch_bounds__(256) void pooled_proj_kernel(
    const bf16* __restrict__ pa, const bf16* __restrict__ w,
    const bf16* __restrict__ bias, bf16* __restrict__ pooled) {
    const int b = blockIdx.x, t = threadIdx.x;
    __shared__ float xs[256];
    xs[t] = (float)pa[b * 256 + t];
    __syncthreads();
    float acc = (float)bias[t];
    for (int k = 0; k < 256; k++) acc += xs[k] * (float)w[t * 256 + k];
    pooled[b * 256 + t] = (bf16)acc;
}

__global__ __launch_bounds__(256) void heads_kernel(
    const bf16* __restrict__ pooled,
    const bf16* __restrict__ aw1, const bf16* __restrict__ ab1,
    const bf16* __restrict__ aln1s, const bf16* __restrict__ aln1b,
    const bf16* __restrict__ aw2, const bf16* __restrict__ ab2,
    const bf16* __restrict__ aln2s, const bf16* __restrict__ aln2b,
    const bf16* __restrict__ aw3, const bf16* __restrict__ ab3,
    const bf16* __restrict__ pw1, const bf16* __restrict__ pb1,
    const bf16* __restrict__ pln1s, const bf16* __restrict__ pln1b,
    const bf16* __restrict__ pw2, const bf16* __restrict__ pb2,
    const bf16* __restrict__ pln2s, const bf16* __restrict__ pln2b,
    const bf16* __restrict__ pw3, const bf16* __restrict__ pb3,
    float* __restrict__ out) {
    const int b = blockIdx.x, t = threadIdx.x;
    __shared__ float pool[256], buf[256], buf2[256], r1[256], r2[256];
    pool[t] = (float)pooled[b * 256 + t];
    __syncthreads();

    auto block_ln = [&](float* v, int W, const bf16* ls, const bf16* lb) {
        const float val = (t < W) ? v[t] : 0.0f;
        r1[t] = val;
        r2[t] = val * val;
        __syncthreads();
        for (int off = 128; off > 0; off >>= 1) {
            if (t < off) { r1[t] += r1[t + off]; r2[t] += r2[t + off]; }
            __syncthreads();
        }
        const float mean = r1[0] / (float)W;
        const float var = fmaxf(r2[0] / (float)W - mean * mean, 0.0f);
        const float inv = rsqrtf(var + 1e-5f);
        __syncthreads();
        if (t < W) v[t] = (val - mean) * inv * (float)ls[t] + (float)lb[t];
        __syncthreads();
    };

    float a;
    if (t < 128) {
        a = (float)ab1[t];
        for (int k = 0; k < 256; k++) a += pool[k] * (float)aw1[t * 256 + k];
        buf[t] = gelu_exact(a);
    }
    __syncthreads();
    block_ln(buf, 128, aln1s, aln1b);
    if (t < 64) {
        a = (float)ab2[t];
        for (int k = 0; k < 128; k++) a += buf[k] * (float)aw2[t * 128 + k];
        buf2[t] = gelu_exact(a);
    }
    __syncthreads();
    block_ln(buf2, 64, aln2s, aln2b);
    if (t < 3) {
        a = (float)ab3[t];
        for (int k = 0; k < 64; k++) a += buf2[k] * (float)aw3[t * 64 + k];
        out[b * 3 + t] = a;
    }

    a = (float)pb1[t];
    for (int k = 0; k < 256; k++) a += pool[k] * (float)pw1[t * 256 + k];
    buf[t] = a;
    __syncthreads();
    block_ln(buf, 256, pln1s, pln1b);
    buf[t] = gelu_exact(buf[t]);
    __syncthreads();
    if (t < 128) {
        a = (float)pb2[t];
        for (int k = 0; k < 256; k++) a += buf[k] * (float)pw2[t * 256 + k];
        buf2[t] = a;
    }
    __syncthreads();
    block_ln(buf2, 128, pln2s, pln2b);
    if (t < 128) buf2[t] = gelu_exact(buf2[t]);
    __syncthreads();
    if (t == 0) {
        a = (float)pb3[0];
        for (int k = 0; k < 128; k++) a += buf2[k] * (float)pw3[k];
        out[48 + b] = a;
    }
}

__global__ void aux_kernel(const float* __restrict__ sums, float* __restrict__ out) {
    if (threadIdx.x == 0 && blockIdx.x == 0) {
        float tot = 0.0f;
        for (int l = 0; l < 6; l++)
            for (int e = 0; e < 8; e++) {
                const float mn = sums[l * 8 + e] * (1.0f / 8192.0f);
                tot += 8.0f * mn * mn;
            }
        out[64] = tot;
    }
}

// ---------------------------------------------------------------------------
extern "C" void kernel_launch(void* const* d_in, const int* in_sizes, int n_in,
                              void* d_out, int out_size, void* d_ws, size_t ws_size,
                              hipStream_t stream) {
    char* ws = (char*)d_ws;
    bf16*  h     = (bf16*)(ws);                         // 8193x256
    bf16*  moe   = (bf16*)(ws + 4456448);               // 8193x256
    char*  ctrl  = ws + 8912896;
    float* auxs   = (float*)(ctrl + 0);                 // 48 f32
    int*   flag   = (int*)(ctrl + 192);
    int*   ntiles = (int*)(ctrl + 256);                 // [2]
    int*   tileex = (int*)(ctrl + 320);                 // [2][72]
    float* ostage = (float*)(ctrl + 1024);              // 65 f32
    int*   g_hist = (int*)(ctrl + 2048);                // [64][16]
    int*   boff   = (int*)(ctrl + 6144);                // [64][16]
    int*   top_e  = (int*)(ctrl + 10240);               // [2][8192]
    float* top_w  = (float*)(ctrl + 75776);             // [2][8192]
    int*   list   = (int*)(ctrl + 141312);              // [2][9216]
    float* lw     = (float*)(ctrl + 215040);            // [2][9216]
    char*  big   = ws + 9961472;
    bf16*  qkv   = (bf16*)(big);                        // 8192x768
    bf16*  aoutb = (bf16*)(big + 12582912);             // 8192x256
    bf16*  projo = (bf16*)(big);                        // reuse (qkv dead)
    bf16*  hid   = (bf16*)(big);                        // 9216x1024 (reuse all)
    bf16*  pattn  = (bf16*)(ws + 29360128);
    bf16*  pooled = (bf16*)(ws + 29360128 + 8192);
    bf16*  cvbase = (bf16*)(ws + 29376512);             // ~10.1 MB

    InTab tab;
    unsigned off = 0;
    bf16* cv[NIN];
    for (int i = 0; i < NIN; i++) {
        tab.src[i] = d_in[i];
        tab.off[i] = off;
        tab.n[i] = (unsigned)in_sizes[i];
        cv[i] = cvbase + off;
        off += ((unsigned)in_sizes[i] + 7u) & ~7u;
    }

    const bf16 *x = cv[0], *in_w = cv[1], *in_b = cv[2], *qkv_w = cv[3], *qkv_b = cv[4],
               *out_w = cv[5], *out_b = cv[6], *gate_w = cv[7], *gate_b = cv[8],
               *e_w1 = cv[9], *e_b1 = cv[10], *e_w2 = cv[11], *e_b2 = cv[12],
               *ln1_s = cv[13], *ln1_b = cv[14], *ln2_s = cv[15], *ln2_b = cv[16],
               *pqkv_w = cv[17], *pqkv_b = cv[18], *pout_w = cv[19], *pout_b = cv[20],
               *a_w1 = cv[21], *a_b1 = cv[22], *a_ln1s = cv[23], *a_ln1b = cv[24],
               *a_w2 = cv[25], *a_b2 = cv[26], *a_ln2s = cv[27], *a_ln2b = cv[28],
               *a_w3 = cv[29], *a_b3 = cv[30],
               *pr_w1 = cv[31], *pr_b1 = cv[32], *pr_ln1s = cv[33], *pr_ln1b = cv[34],
               *pr_w2 = cv[35], *pr_b2 = cv[36], *pr_ln2s = cv[37], *pr_ln2b = cv[38],
               *pr_w3 = cv[39], *pr_b3 = cv[40];

    sniff_kernel<<<1, 256, 0, stream>>>((const unsigned*)d_in[0], flag);
    convert_kernel<<<dim3(2048, NIN), 256, 0, stream>>>(tab, cvbase, flag);

    hipMemsetAsync(auxs, 0, 192, stream);
    input_proj_kernel<<<8192, 256, 0, stream>>>(x, in_w, in_b, h);

    for (int l = 0; l < 6; l++) {
        gemm_bt<128, 128, 64, 64><<<dim3(64, 6), 256, 0, stream>>>(
            h, qkv_w, qkv_b, qkv, 8192, 768, 256);
        attn_kernel<<<dim3(16, 128), 256, 0, stream>>>(qkv, aoutb);
        gemm_bt<128, 64, 32, 64><<<dim3(64, 4), 256, 0, stream>>>(
            aoutb, out_w, out_b, projo, 8192, 256, 256);
        ln_kernel<<<8192, 256, 0, stream>>>(h, projo, ln1_s, ln1_b);

        // routing (atomic-free counting sort)
        gate_kernel<<<64, 256, 0, stream>>>(h, gate_w, gate_b,
                                            top_e, top_w, g_hist, auxs + l * 8);
        route_build_kernel<<<1, 256, 0, stream>>>(g_hist, boff, ntiles, tileex, list, lw);
        scatter_kernel<<<64, 256, 0, stream>>>(top_e, top_w, boff, list, lw);

        // top-2 expert FFN (slot 0 covers every token: write; slot 1: accumulate)
        for (int slot = 0; slot < 2; slot++) {
            gemm_moe<128, 128, 64, 64, 1><<<dim3(71, 8), 256, 0, stream>>>(
                h, e_w1, e_b1, hid, 1024, 256,
                list + slot * 9216, lw + slot * 9216, tileex + slot * 72, ntiles + slot);
            if (slot == 0)
                gemm_moe<128, 64, 32, 64, 2><<<dim3(71, 4), 256, 0, stream>>>(
                    hid, e_w2, e_b2, moe, 256, 1024,
                    list, lw, tileex, ntiles);
            else
                gemm_moe<128, 64, 32, 64, 3><<<dim3(71, 4), 256, 0, stream>>>(
                    hid, e_w2, e_b2, moe, 256, 1024,
                    list + 9216, lw + 9216, tileex + 72, ntiles + 1);
        }
        ln_kernel<<<8192, 256, 0, stream>>>(h, moe, ln2_s, ln2_b);
    }

    gemm_bt<128, 128, 64, 64><<<dim3(64, 6), 256, 0, stream>>>(
        h, pqkv_w, pqkv_b, qkv, 8192, 768, 256);
    pooled_attn_kernel<<<32, 256, 0, stream>>>(qkv, pattn);
    pooled_proj_kernel<<<16, 256, 0, stream>>>(pattn, pout_w, pout_b, pooled);

    heads_kernel<<<16, 256, 0, stream>>>(
        pooled,
        a_w1, a_b1, a_ln1s, a_ln1b, a_w2, a_b2, a_ln2s, a_ln2b, a_w3, a_b3,
        pr_w1, pr_b1, pr_ln1s, pr_ln1b, pr_w2, pr_b2, pr_ln2s, pr_ln2b, pr_w3, pr_b3,
        ostage);
    aux_kernel<<<1, 64, 0, stream>>>(auxs, ostage);
    out_convert_kernel<<<1, 128, 0, stream>>>(ostage, d_out, flag);
}

// Round 5
// 1407.238 us; speedup vs baseline: 2.0005x; 1.0548x over previous
//
#include <hip/hip_runtime.h>
#include <hip/hip_bf16.h>
#include <math.h>

// ---------------------------------------------------------------------------
// MoE trading transformer forward, MI355X/gfx950.
// B=16 S=512 F_IN=46 D=256 H=8 (dh=32) L=6 E=8 DFF=1024 OUT=3.
// R5: attention V pre-transposed by the QKV GEMM epilogue (vT[b][h][d][s]),
// PV reads B-fragments straight from global; softmax 1/se folded into the
// PV epilogue (2 LDS passes instead of 3, no V staging, no extra syncs).
// Wave-per-token LayerNorm. Compact convert grid.
// ws_size = 256 MB (measured via harness poison WRITE_SIZE); layout below
// uses < 48 MB.
// ---------------------------------------------------------------------------

typedef __bf16 bf16;
typedef __bf16 bf16x8 __attribute__((ext_vector_type(8)));
typedef __bf16 bf16x4 __attribute__((ext_vector_type(4)));
typedef float f32x4 __attribute__((ext_vector_type(4)));

#define NIN 41

struct InTab {
    const void* src[NIN];
    unsigned off[NIN];   // 1024-aligned element prefix offsets into cvbase
    unsigned n[NIN];
};

__device__ __forceinline__ float gelu_exact(float x) {
    return 0.5f * x * (1.0f + erff(x * 0.70710678118654752f));
}

// ---------------------------------------------------------------------------
// Dtype sniffer (f32 vs bf16 storage). flag: 1=bf16, 0=f32.
// ---------------------------------------------------------------------------
__global__ void sniff_kernel(const unsigned* __restrict__ xw, int* __restrict__ flag) {
    __shared__ int cnt;
    if (threadIdx.x == 0) cnt = 0;
    __syncthreads();
    const unsigned w = xw[threadIdx.x];
    const unsigned ex = (w >> 7) & 0xFFu;
    if (ex >= 107u && ex <= 133u) atomicAdd(&cnt, 1);
    __syncthreads();
    if (threadIdx.x == 0) *flag = (cnt >= 192) ? 1 : 0;
}

// Compact 1D grid: each block converts 1024 elements of one input.
__global__ __launch_bounds__(256) void convert_kernel(
    InTab tab, bf16* __restrict__ dst_base, const int* __restrict__ flag) {
    const unsigned g0 = blockIdx.x * 1024u;
    int inp = 0;
#pragma unroll
    for (int i = 1; i < NIN; i++)
        if (g0 >= tab.off[i]) inp = i;
    const unsigned n = tab.n[inp];
    const unsigned i0 = g0 - tab.off[inp] + threadIdx.x * 4u;
    if (i0 >= n) return;
    const int isbf = *flag;
    bf16* dst = dst_base + tab.off[inp];
    const unsigned end = (i0 + 4u > n) ? n : i0 + 4u;
    if (isbf) {
        const unsigned short* s = (const unsigned short*)tab.src[inp];
        for (unsigned i = i0; i < end; i++) ((unsigned short*)dst)[i] = s[i];
    } else {
        const float* s = (const float*)tab.src[inp];
        for (unsigned i = i0; i < end; i++) dst[i] = (bf16)s[i];
    }
}

__global__ void out_convert_kernel(const float* __restrict__ st, void* __restrict__ out,
                                   const int* __restrict__ flag) {
    const int i = threadIdx.x;
    if (i >= 65) return;
    if (*flag) ((bf16*)out)[i] = (bf16)st[i];
    else       ((float*)out)[i] = st[i];
}

// ---------------------------------------------------------------------------
// Dense MFMA GEMM:  C[M,N] = A[M,K] @ W[N,K]^T + bias[N]
// VTOUT: output columns gn>=512 are the V projection -> written transposed
// into vT[b][h][d][s] (for attention PV / pooled attention) instead of C.
// ---------------------------------------------------------------------------
template <int BM, int BN, int WM, int WN, bool VTOUT>
__global__ __launch_bounds__(256) void gemm_bt(
    const bf16* __restrict__ A, const bf16* __restrict__ W,
    const bf16* __restrict__ bias, bf16* __restrict__ C,
    int M, int N, int K, bf16* __restrict__ vT) {
    constexpr int BK = 64;
    __shared__ alignas(16) bf16 As[BM][BK + 8];
    __shared__ alignas(16) bf16 Ws[BN][BK + 8];
    const int bm0 = blockIdx.x * BM, bn0 = blockIdx.y * BN;
    const int tid = threadIdx.x;
    const int wave = tid >> 6, lane = tid & 63;
    constexpr int WCOLS = BN / WN;
    const int wm0 = (wave / WCOLS) * WM, wn0 = (wave % WCOLS) * WN;
    constexpr int MT = WM / 16, NT = WN / 16;
    f32x4 acc[MT][NT] = {};
    const int lrow = tid >> 3, lcol = (tid & 7) * 8;
    const int frow = lane & 15, fquad = lane >> 4;

    for (int k0 = 0; k0 < K; k0 += BK) {
#pragma unroll
        for (int p = 0; p < BM / 32; p++)
            *(bf16x8*)&As[lrow + p * 32][lcol] =
                *(const bf16x8*)&A[(size_t)(bm0 + lrow + p * 32) * K + k0 + lcol];
#pragma unroll
        for (int p = 0; p < BN / 32; p++)
            *(bf16x8*)&Ws[lrow + p * 32][lcol] =
                *(const bf16x8*)&W[(size_t)(bn0 + lrow + p * 32) * K + k0 + lcol];
        __syncthreads();
#pragma unroll
        for (int ks = 0; ks < BK / 32; ks++) {
            bf16x8 af[MT], bfr[NT];
#pragma unroll
            for (int mt = 0; mt < MT; mt++)
                af[mt] = *(const bf16x8*)&As[wm0 + mt * 16 + frow][ks * 32 + fquad * 8];
#pragma unroll
            for (int nt = 0; nt < NT; nt++)
                bfr[nt] = *(const bf16x8*)&Ws[wn0 + nt * 16 + frow][ks * 32 + fquad * 8];
#pragma unroll
            for (int mt = 0; mt < MT; mt++)
#pragma unroll
                for (int nt = 0; nt < NT; nt++)
                    acc[mt][nt] = __builtin_amdgcn_mfma_f32_16x16x32_bf16(
                        af[mt], bfr[nt], acc[mt][nt], 0, 0, 0);
        }
        __syncthreads();
    }

#pragma unroll
    for (int mt = 0; mt < MT; mt++)
#pragma unroll
        for (int nt = 0; nt < NT; nt++) {
            const int gn = bn0 + wn0 + nt * 16 + frow;
            const float bv = (float)bias[gn];
#pragma unroll
            for (int r = 0; r < 4; r++) {
                const int gm = bm0 + wm0 + mt * 16 + fquad * 4 + r;
                const float v = acc[mt][nt][r] + bv;
                if (VTOUT && gn >= 512) {
                    const int d = gn - 512;          // h = d>>5, dd = d&31
                    const int bb = gm >> 9, s = gm & 511;
                    vT[((size_t)(bb * 8 + (d >> 5)) * 32 + (d & 31)) * 512 + s] = (bf16)v;
                } else {
                    C[(size_t)gm * N + gn] = (bf16)v;
                }
            }
        }
}

// ---------------------------------------------------------------------------
// Routed MoE GEMM over a compacted token list.
// MODE 1: hid[i] = GELU(h[list[i]] @ w1_e^T + b1_e)      (N=1024,K=256)
// MODE 2: moe[list[i]]  = lw[i]*(hid[i] @ w2_e^T + b2_e) (N=256, K=1024)
// MODE 3: moe[list[i]] += lw[i]*(...)
// ---------------------------------------------------------------------------
template <int BM, int BN, int WM, int WN, int MODE>
__global__ __launch_bounds__(256) void gemm_moe(
    const bf16* __restrict__ A, const bf16* __restrict__ Wb,
    const bf16* __restrict__ biasb, bf16* __restrict__ C,
    int N, int K, const int* __restrict__ list, const float* __restrict__ lw,
    const int* __restrict__ tile_ex, const int* __restrict__ ntiles) {
    if ((int)blockIdx.x >= *ntiles) return;
    constexpr int BK = 64;
    __shared__ alignas(16) bf16 As[BM][BK + 8];
    __shared__ alignas(16) bf16 Ws[BN][BK + 8];
    const int e = tile_ex[blockIdx.x];
    const bf16* W = Wb + (size_t)e * N * K;
    const bf16* bias = biasb + e * N;
    const int bm0 = blockIdx.x * BM, bn0 = blockIdx.y * BN;
    const int tid = threadIdx.x;
    const int wave = tid >> 6, lane = tid & 63;
    constexpr int WCOLS = BN / WN;
    const int wm0 = (wave / WCOLS) * WM, wn0 = (wave % WCOLS) * WN;
    constexpr int MT = WM / 16, NT = WN / 16;
    f32x4 acc[MT][NT] = {};
    const int lrow = tid >> 3, lcol = (tid & 7) * 8;
    const int frow = lane & 15, fquad = lane >> 4;

    int arow[BM / 32];
#pragma unroll
    for (int p = 0; p < BM / 32; p++) {
        const int r = bm0 + lrow + p * 32;
        arow[p] = (MODE == 1) ? list[r] : r;
    }

    for (int k0 = 0; k0 < K; k0 += BK) {
#pragma unroll
        for (int p = 0; p < BM / 32; p++)
            *(bf16x8*)&As[lrow + p * 32][lcol] =
                *(const bf16x8*)&A[(size_t)arow[p] * K + k0 + lcol];
#pragma unroll
        for (int p = 0; p < BN / 32; p++)
            *(bf16x8*)&Ws[lrow + p * 32][lcol] =
                *(const bf16x8*)&W[(size_t)(bn0 + lrow + p * 32) * K + k0 + lcol];
        __syncthreads();
#pragma unroll
        for (int ks = 0; ks < BK / 32; ks++) {
            bf16x8 af[MT], bfr[NT];
#pragma unroll
            for (int mt = 0; mt < MT; mt++)
                af[mt] = *(const bf16x8*)&As[wm0 + mt * 16 + frow][ks * 32 + fquad * 8];
#pragma unroll
            for (int nt = 0; nt < NT; nt++)
                bfr[nt] = *(const bf16x8*)&Ws[wn0 + nt * 16 + frow][ks * 32 + fquad * 8];
#pragma unroll
            for (int mt = 0; mt < MT; mt++)
#pragma unroll
                for (int nt = 0; nt < NT; nt++)
                    acc[mt][nt] = __builtin_amdgcn_mfma_f32_16x16x32_bf16(
                        af[mt], bfr[nt], acc[mt][nt], 0, 0, 0);
        }
        __syncthreads();
    }

#pragma unroll
    for (int mt = 0; mt < MT; mt++)
#pragma unroll
        for (int nt = 0; nt < NT; nt++) {
            const int gn = bn0 + wn0 + nt * 16 + frow;
            const float bv = (float)bias[gn];
#pragma unroll
            for (int r = 0; r < 4; r++) {
                const int gm = bm0 + wm0 + mt * 16 + fquad * 4 + r;
                const float v = acc[mt][nt][r] + bv;
                if (MODE == 1) {
                    C[(size_t)gm * N + gn] = (bf16)gelu_exact(v);
                } else {
                    const int token = list[gm];
                    const float s = lw[gm];
                    bf16* dst = &C[(size_t)token * 256 + gn];
                    if (MODE == 2) *dst = (bf16)(s * v);
                    else           *dst = (bf16)((float)*dst + s * v);
                }
            }
        }
}

// ---------------------------------------------------------------------------
// Input projection + positional encoding. grid 8192, block 256.
// ---------------------------------------------------------------------------
__global__ __launch_bounds__(256) void input_proj_kernel(
    const bf16* __restrict__ x, const bf16* __restrict__ w,
    const bf16* __restrict__ b, bf16* __restrict__ h) {
    const int m = blockIdx.x, t = threadIdx.x;
    __shared__ float xs[46];
    if (t < 46) xs[t] = (float)x[m * 46 + t];
    __syncthreads();
    float acc = (float)b[t];
#pragma unroll
    for (int k = 0; k < 46; k++) acc += xs[k] * (float)w[t * 46 + k];
    const int s = m & 511;
    const int i = t >> 1;
    const float dv = expf((float)(2 * i) * (-9.210340371976184f / 256.0f));
    const float ang = (float)s * dv;
    const float pe = (t & 1) ? cosf(ang) : sinf(ang);
    h[(size_t)m * 256 + t] = (bf16)(acc + pe);
}

// ---------------------------------------------------------------------------
// Wave-per-token LayerNorm with bf16 residual add: h = LN(h+add)*s + b.
// grid 2048 x 256 (4 tokens/block, 1 wave each; no LDS, no __syncthreads).
// ---------------------------------------------------------------------------
__global__ __launch_bounds__(256) void ln_kernel(
    bf16* __restrict__ h, const bf16* __restrict__ add,
    const bf16* __restrict__ s, const bf16* __restrict__ b) {
    const int m = blockIdx.x * 4 + (threadIdx.x >> 6);
    const int lane = threadIdx.x & 63;
    const int c0 = lane * 4;
    bf16x4 hv = *(const bf16x4*)&h[(size_t)m * 256 + c0];
    bf16x4 av = *(const bf16x4*)&add[(size_t)m * 256 + c0];
    float x[4];
    float s1 = 0.0f, s2 = 0.0f;
#pragma unroll
    for (int j = 0; j < 4; j++) {
        x[j] = (float)hv[j] + (float)av[j];
        s1 += x[j];
        s2 += x[j] * x[j];
    }
#pragma unroll
    for (int msk = 1; msk < 64; msk <<= 1) {
        s1 += __shfl_xor(s1, msk, 64);
        s2 += __shfl_xor(s2, msk, 64);
    }
    const float mean = s1 * (1.0f / 256.0f);
    const float var = fmaxf(s2 * (1.0f / 256.0f) - mean * mean, 0.0f);
    const float inv = rsqrtf(var + 1e-5f);
    bf16x4 sv = *(const bf16x4*)&s[c0];
    bf16x4 bv = *(const bf16x4*)&b[c0];
    bf16x4 o;
#pragma unroll
    for (int j = 0; j < 4; j++)
        o[j] = (bf16)((x[j] - mean) * inv * (float)sv[j] + (float)bv[j]);
    *(bf16x4*)&h[(size_t)m * 256 + c0] = o;
}

// ---------------------------------------------------------------------------
// Gate: grid 64 x 256, 128 tokens/block. Logits -> top-2 -> per-block LDS
// histogram -> plain store. No per-token global atomics.
// ---------------------------------------------------------------------------
__global__ __launch_bounds__(256) void gate_kernel(
    const bf16* __restrict__ h, const bf16* __restrict__ gw,
    const bf16* __restrict__ gb, int* __restrict__ top_e,
    float* __restrict__ top_w, int* __restrict__ g_hist,
    float* __restrict__ aux_sums) {
    __shared__ float lg[128][9];
    __shared__ float mxs[128], invs[128];
    __shared__ int hist[16];
    const int tid = threadIdx.x;
    if (tid < 16) hist[tid] = 0;
    const int e = tid & 7;
#pragma unroll
    for (int pass = 0; pass < 4; pass++) {
        const int tl = pass * 32 + (tid >> 3);
        const int tok = blockIdx.x * 128 + tl;
        float acc = 0.0f;
        for (int k = 0; k < 256; k += 8) {
            bf16x8 hv = *(const bf16x8*)&h[(size_t)tok * 256 + k];
            bf16x8 wv = *(const bf16x8*)&gw[e * 256 + k];
#pragma unroll
            for (int j = 0; j < 8; j++) acc += (float)hv[j] * (float)wv[j];
        }
        lg[tl][e] = acc + (float)gb[e];
    }
    __syncthreads();
    if (tid < 128) {
        const int tok = blockIdx.x * 128 + tid;
        float l[8];
#pragma unroll
        for (int j = 0; j < 8; j++) l[j] = lg[tid][j];
        int i0 = 0;
#pragma unroll
        for (int j = 1; j < 8; j++)
            if (l[j] > l[i0]) i0 = j;
        int i1 = -1;
#pragma unroll
        for (int j = 0; j < 8; j++)
            if (j != i0 && (i1 < 0 || l[j] > l[i1])) i1 = j;
        const float p0 = 1.0f / (1.0f + expf(l[i1] - l[i0]));
        top_e[tok] = i0;         top_w[tok] = p0;
        top_e[8192 + tok] = i1;  top_w[8192 + tok] = 1.0f - p0;
        atomicAdd(&hist[i0], 1);
        atomicAdd(&hist[8 + i1], 1);
        const float mx = l[i0];
        float se = 0.0f;
#pragma unroll
        for (int j = 0; j < 8; j++) se += expf(l[j] - mx);
        mxs[tid] = mx;
        invs[tid] = 1.0f / se;
    }
    __syncthreads();
    if (tid < 8) {
        float s = 0.0f;
        for (int t = 0; t < 128; t++) s += expf(lg[t][tid] - mxs[t]) * invs[t];
        atomicAdd(&aux_sums[tid], s);
    }
    if (tid < 16) g_hist[blockIdx.x * 16 + tid] = hist[tid];
}

// ---------------------------------------------------------------------------
// Build routing tables from per-block histograms. Single block.
// ---------------------------------------------------------------------------
__global__ void route_build_kernel(
    const int* __restrict__ g_hist, int* __restrict__ boff,
    int* __restrict__ ntiles, int* __restrict__ tile_ex,
    int* __restrict__ list, float* __restrict__ lw) {
    const int tid = threadIdx.x;
    __shared__ int s_pre[64][16];
    __shared__ int s_cnt[16];
    __shared__ int s_off[16];
    if (tid < 16) {
        int run = 0;
        for (int b = 0; b < 64; b++) {
            s_pre[b][tid] = run;
            run += g_hist[b * 16 + tid];
        }
        s_cnt[tid] = run;
    }
    __syncthreads();
    if (tid < 2) {
        const int slot = tid;
        int o = 0;
        for (int e2 = 0; e2 < 8; e2++) {
            s_off[slot * 8 + e2] = o;
            const int nt = (s_cnt[slot * 8 + e2] + 127) >> 7;
            for (int t = 0; t < nt; t++) tile_ex[slot * 72 + (o >> 7) + t] = e2;
            o += nt << 7;
        }
        ntiles[slot] = o >> 7;
    }
    __syncthreads();
    if (tid < 16) {
        for (int b = 0; b < 64; b++)
            boff[b * 16 + tid] = s_off[tid] + s_pre[b][tid];
    }
    for (int idx = tid; idx < 16 * 128; idx += 256) {
        const int seg = idx >> 7, i = idx & 127;
        const int slot = seg >> 3;
        const int start = s_off[seg] + s_cnt[seg];
        const int end = s_off[seg] + ((s_cnt[seg] + 127) & ~127);
        const int p = start + i;
        if (p < end) {
            list[slot * 9216 + p] = 8192;
            lw[slot * 9216 + p] = 0.0f;
        }
    }
}

// Scatter tokens into expert segments. grid 64 x 256. LDS atomics only.
__global__ __launch_bounds__(256) void scatter_kernel(
    const int* __restrict__ top_e, const float* __restrict__ top_w,
    const int* __restrict__ boff, int* __restrict__ list,
    float* __restrict__ lw) {
    __shared__ int pos[16];
    const int tid = threadIdx.x;
    if (tid < 16) pos[tid] = boff[blockIdx.x * 16 + tid];
    __syncthreads();
    if (tid < 128) {
        const int tok = blockIdx.x * 128 + tid;
#pragma unroll
        for (int slot = 0; slot < 2; slot++) {
            const int e = top_e[slot * 8192 + tok];
            const float w = top_w[slot * 8192 + tok];
            const int idx = atomicAdd(&pos[slot * 8 + e], 1);
            list[slot * 9216 + idx] = tok;
            lw[slot * 9216 + idx] = w;
        }
    }
}

// ---------------------------------------------------------------------------
// Fused attention, one (b,h) x 32-query tile per block. grid (16,128).
// R5: V from pre-transposed vT (global bf16x8 loads, no LDS staging);
// 1/se folded into PV epilogue (2 softmax LDS passes).
// ---------------------------------------------------------------------------
__global__ __launch_bounds__(256) void attn_kernel(
    const bf16* __restrict__ qkv, const bf16* __restrict__ vT,
    bf16* __restrict__ aout) {
    __shared__ alignas(16) bf16 P[32][520];
    __shared__ float sinv[32];
    const int s0 = blockIdx.x * 32;
    const int b = blockIdx.y >> 3, hh = blockIdx.y & 7;
    const int tid = threadIdx.x, wave = tid >> 6, lane = tid & 63;
    const int frow = lane & 15, fquad = lane >> 4;
    const size_t base = (size_t)b * 512;
    const float scale = 0.17677669529663687f;  // 1/sqrt(32)

    // ---- S = Q K^T * scale ----
    bf16x8 qf[2];
#pragma unroll
    for (int mt = 0; mt < 2; mt++)
        qf[mt] = *(const bf16x8*)&qkv[(base + s0 + mt * 16 + frow) * 768 + hh * 32 + fquad * 8];
#pragma unroll
    for (int k8 = 0; k8 < 8; k8++) {
        const int key0 = (wave * 8 + k8) * 16;
        bf16x8 kf = *(const bf16x8*)&qkv[(base + key0 + frow) * 768 + 256 + hh * 32 + fquad * 8];
#pragma unroll
        for (int mt = 0; mt < 2; mt++) {
            f32x4 c = {};
            c = __builtin_amdgcn_mfma_f32_16x16x32_bf16(qf[mt], kf, c, 0, 0, 0);
#pragma unroll
            for (int r = 0; r < 4; r++)
                P[mt * 16 + fquad * 4 + r][key0 + frow] = (bf16)(c[r] * scale);
        }
    }
    __syncthreads();

    // ---- softmax (unnormalized): max pass + exp/sum pass; 1/se to sinv ----
    {
        const int row = tid >> 3, c0 = tid & 7;
        float mx = -1e30f;
        for (int j = 0; j < 64; j++) mx = fmaxf(mx, (float)P[row][c0 + 8 * j]);
#pragma unroll
        for (int msk = 1; msk < 8; msk <<= 1) mx = fmaxf(mx, __shfl_xor(mx, msk, 64));
        float se = 0.0f;
        for (int j = 0; j < 64; j++) {
            const float e_ = expf((float)P[row][c0 + 8 * j] - mx);
            se += e_;
            P[row][c0 + 8 * j] = (bf16)e_;
        }
#pragma unroll
        for (int msk = 1; msk < 8; msk <<= 1) se += __shfl_xor(se, msk, 64);
        if (c0 == 0) sinv[row] = 1.0f / se;
    }
    __syncthreads();

    // ---- O = (P V) * 1/se, V fragments straight from vT ----
    {
        const int mt = wave >> 1, nt = wave & 1;
        const bf16* vrow = &vT[((size_t)(b * 8 + hh) * 32 + nt * 16 + frow) * 512];
        f32x4 o = {};
#pragma unroll
        for (int ks = 0; ks < 16; ks++) {
            bf16x8 pf = *(const bf16x8*)&P[mt * 16 + frow][ks * 32 + fquad * 8];
            bf16x8 vf = *(const bf16x8*)&vrow[ks * 32 + fquad * 8];
            o = __builtin_amdgcn_mfma_f32_16x16x32_bf16(pf, vf, o, 0, 0, 0);
        }
        const int r0 = mt * 16 + fquad * 4;
#pragma unroll
        for (int r = 0; r < 4; r++)
            aout[(base + s0 + r0 + r) * 256 + hh * 32 + nt * 16 + frow] =
                (bf16)(o[r] * sinv[r0 + r]);
    }
}

// ---------------------------------------------------------------------------
// Pooled attention (last-token query), V from vT (coalesced). grid 32.
// ---------------------------------------------------------------------------
__global__ __launch_bounds__(256) void pooled_attn_kernel(
    const bf16* __restrict__ qkv, const bf16* __restrict__ vT,
    bf16* __restrict__ pa) {
    const int wid = blockIdx.x * 4 + (threadIdx.x >> 6);
    const int lane = threadIdx.x & 63;
    const int b = wid >> 3, hh = wid & 7;
    const size_t base = (size_t)b * 512;
    const float scale = 0.17677669529663687f;
    float q[32];
#pragma unroll
    for (int d = 0; d < 32; d++) q[d] = (float)qkv[(base + 511) * 768 + hh * 32 + d];
    float sc[8];
    float mx = -1e30f;
#pragma unroll
    for (int j = 0; j < 8; j++) {
        const int key = lane + j * 64;
        const bf16* kr = &qkv[(base + key) * 768 + 256 + hh * 32];
        float s = 0.0f;
#pragma unroll
        for (int d = 0; d < 32; d++) s += q[d] * (float)kr[d];
        s *= scale;
        sc[j] = s;
        mx = fmaxf(mx, s);
    }
#pragma unroll
    for (int m = 1; m < 64; m <<= 1) mx = fmaxf(mx, __shfl_xor(mx, m, 64));
    float se = 0.0f;
#pragma unroll
    for (int j = 0; j < 8; j++) { sc[j] = expf(sc[j] - mx); se += sc[j]; }
#pragma unroll
    for (int m = 1; m < 64; m <<= 1) se += __shfl_xor(se, m, 64);
    float o[32] = {};
    const bf16* vb = &vT[(size_t)(b * 8 + hh) * 32 * 512];
#pragma unroll
    for (int d = 0; d < 32; d++) {
        const bf16* vr = vb + (size_t)d * 512;
#pragma unroll
        for (int j = 0; j < 8; j++)
            o[d] += sc[j] * (float)vr[lane + j * 64];
    }
#pragma unroll
    for (int d = 0; d < 32; d++) {
#pragma unroll
        for (int m = 1; m < 64; m <<= 1) o[d] += __shfl_xor(o[d], m, 64);
    }
    if (lane == 0) {
        const float inv = 1.0f / se;
        for (int d = 0; d < 32; d++) pa[b * 256 + hh * 32 + d] = (bf16)(o[d] * inv);
    }
}

__global__ __launch_bounds__(256) void pooled_proj_kernel(
    const bf16* __restrict__ pa, const bf16* __restrict__ w,
    const bf16* __restrict__ bias, bf16* __restrict__ pooled) {
    const int b = blockIdx.x, t = threadIdx.x;
    __shared__ float xs[256];
    xs[t] = (float)pa[b * 256 + t];
    __syncthreads();
    float acc = (float)bias[t];
    for (int k = 0; k < 256; k++) acc += xs[k] * (float)w[t * 256 + k];
    pooled[b * 256 + t] = (bf16)acc;
}

__global__ __launch_bounds__(256) void heads_kernel(
    const bf16* __restrict__ pooled,
    const bf16* __restrict__ aw1, const bf16* __restrict__ ab1,
    const bf16* __restrict__ aln1s, const bf16* __restrict__ aln1b,
    const bf16* __restrict__ aw2, const bf16* __restrict__ ab2,
    const bf16* __restrict__ aln2s, const bf16* __restrict__ aln2b,
    const bf16* __restrict__ aw3, const bf16* __restrict__ ab3,
    const bf16* __restrict__ pw1, const bf16* __restrict__ pb1,
    const bf16* __restrict__ pln1s, const bf16* __restrict__ pln1b,
    const bf16* __restrict__ pw2, const bf16* __restrict__ pb2,
    const bf16* __restrict__ pln2s, const bf16* __restrict__ pln2b,
    const bf16* __restrict__ pw3, const bf16* __restrict__ pb3,
    float* __restrict__ out) {
    const int b = blockIdx.x, t = threadIdx.x;
    __shared__ float pool[256], buf[256], buf2[256], r1[256], r2[256];
    pool[t] = (float)pooled[b * 256 + t];
    __syncthreads();

    auto block_ln = [&](float* v, int W, const bf16* ls, const bf16* lb) {
        const float val = (t < W) ? v[t] : 0.0f;
        r1[t] = val;
        r2[t] = val * val;
        __syncthreads();
        for (int off = 128; off > 0; off >>= 1) {
            if (t < off) { r1[t] += r1[t + off]; r2[t] += r2[t + off]; }
            __syncthreads();
        }
        const float mean = r1[0] / (float)W;
        const float var = fmaxf(r2[0] / (float)W - mean * mean, 0.0f);
        const float inv = rsqrtf(var + 1e-5f);
        __syncthreads();
        if (t < W) v[t] = (val - mean) * inv * (float)ls[t] + (float)lb[t];
        __syncthreads();
    };

    float a;
    if (t < 128) {
        a = (float)ab1[t];
        for (int k = 0; k < 256; k++) a += pool[k] * (float)aw1[t * 256 + k];
        buf[t] = gelu_exact(a);
    }
    __syncthreads();
    block_ln(buf, 128, aln1s, aln1b);
    if (t < 64) {
        a = (float)ab2[t];
        for (int k = 0; k < 128; k++) a += buf[k] * (float)aw2[t * 128 + k];
        buf2[t] = gelu_exact(a);
    }
    __syncthreads();
    block_ln(buf2, 64, aln2s, aln2b);
    if (t < 3) {
        a = (float)ab3[t];
        for (int k = 0; k < 64; k++) a += buf2[k] * (float)aw3[t * 64 + k];
        out[b * 3 + t] = a;
    }

    a = (float)pb1[t];
    for (int k = 0; k < 256; k++) a += pool[k] * (float)pw1[t * 256 + k];
    buf[t] = a;
    __syncthreads();
    block_ln(buf, 256, pln1s, pln1b);
    buf[t] = gelu_exact(buf[t]);
    __syncthreads();
    if (t < 128) {
        a = (float)pb2[t];
        for (int k = 0; k < 256; k++) a += buf[k] * (float)pw2[t * 256 + k];
        buf2[t] = a;
    }
    __syncthreads();
    block_ln(buf2, 128, pln2s, pln2b);
    if (t < 128) buf2[t] = gelu_exact(buf2[t]);
    __syncthreads();
    if (t == 0) {
        a = (float)pb3[0];
        for (int k = 0; k < 128; k++) a += buf2[k] * (float)pw3[k];
        out[48 + b] = a;
    }
}

__global__ void aux_kernel(const float* __restrict__ sums, float* __restrict__ out) {
    if (threadIdx.x == 0 && blockIdx.x == 0) {
        float tot = 0.0f;
        for (int l = 0; l < 6; l++)
            for (int e = 0; e < 8; e++) {
                const float mn = sums[l * 8 + e] * (1.0f / 8192.0f);
                tot += 8.0f * mn * mn;
            }
        out[64] = tot;
    }
}

// ---------------------------------------------------------------------------
extern "C" void kernel_launch(void* const* d_in, const int* in_sizes, int n_in,
                              void* d_out, int out_size, void* d_ws, size_t ws_size,
                              hipStream_t stream) {
    char* ws = (char*)d_ws;
    const size_t MB = 1024 * 1024;
    bf16*  h     = (bf16*)(ws);                         // 8193x256
    bf16*  moe   = (bf16*)(ws + 4456448);               // 8193x256
    char*  ctrl  = ws + 8912896;
    float* auxs   = (float*)(ctrl + 0);                 // 48 f32
    int*   flag   = (int*)(ctrl + 192);
    int*   ntiles = (int*)(ctrl + 256);                 // [2]
    int*   tileex = (int*)(ctrl + 320);                 // [2][72]
    float* ostage = (float*)(ctrl + 1024);              // 65 f32
    int*   g_hist = (int*)(ctrl + 2048);                // [64][16]
    int*   boff   = (int*)(ctrl + 6144);                // [64][16]
    int*   top_e  = (int*)(ctrl + 10240);               // [2][8192]
    float* top_w  = (float*)(ctrl + 75776);             // [2][8192]
    int*   list   = (int*)(ctrl + 141312);              // [2][9216]
    float* lw     = (float*)(ctrl + 215040);            // [2][9216]
    char*  big   = ws + 9961472;
    bf16*  qkv   = (bf16*)(big);                        // 8192x768 (Q,K used)
    bf16*  aoutb = (bf16*)(big + 12582912);             // 8192x256
    bf16*  projo = (bf16*)(big);                        // reuse (qkv dead)
    bf16*  hid   = (bf16*)(big);                        // 9216x1024 (reuse all)
    bf16*  pattn  = (bf16*)(ws + 29360128);
    bf16*  pooled = (bf16*)(ws + 29360128 + 8192);
    bf16*  cvbase = (bf16*)(ws + 29376512);             // ~10.6 MB (to ~40 MB)
    bf16*  vT    = (bf16*)(ws + 44 * MB);               // [16][8][32][512] = 4 MB

    // canonicalization table: 1024-aligned element offsets
    InTab tab;
    unsigned off = 0;
    bf16* cv[NIN];
    for (int i = 0; i < NIN; i++) {
        tab.src[i] = d_in[i];
        tab.off[i] = off;
        tab.n[i] = (unsigned)in_sizes[i];
        cv[i] = cvbase + off;
        off += ((unsigned)in_sizes[i] + 1023u) & ~1023u;
    }
    const int cv_blocks = (int)(off >> 10);

    const bf16 *x = cv[0], *in_w = cv[1], *in_b = cv[2], *qkv_w = cv[3], *qkv_b = cv[4],
               *out_w = cv[5], *out_b = cv[6], *gate_w = cv[7], *gate_b = cv[8],
               *e_w1 = cv[9], *e_b1 = cv[10], *e_w2 = cv[11], *e_b2 = cv[12],
               *ln1_s = cv[13], *ln1_b = cv[14], *ln2_s = cv[15], *ln2_b = cv[16],
               *pqkv_w = cv[17], *pqkv_b = cv[18], *pout_w = cv[19], *pout_b = cv[20],
               *a_w1 = cv[21], *a_b1 = cv[22], *a_ln1s = cv[23], *a_ln1b = cv[24],
               *a_w2 = cv[25], *a_b2 = cv[26], *a_ln2s = cv[27], *a_ln2b = cv[28],
               *a_w3 = cv[29], *a_b3 = cv[30],
               *pr_w1 = cv[31], *pr_b1 = cv[32], *pr_ln1s = cv[33], *pr_ln1b = cv[34],
               *pr_w2 = cv[35], *pr_b2 = cv[36], *pr_ln2s = cv[37], *pr_ln2b = cv[38],
               *pr_w3 = cv[39], *pr_b3 = cv[40];

    sniff_kernel<<<1, 256, 0, stream>>>((const unsigned*)d_in[0], flag);
    convert_kernel<<<cv_blocks, 256, 0, stream>>>(tab, cvbase, flag);

    hipMemsetAsync(auxs, 0, 192, stream);
    input_proj_kernel<<<8192, 256, 0, stream>>>(x, in_w, in_b, h);

    for (int l = 0; l < 6; l++) {
        gemm_bt<128, 128, 64, 64, true><<<dim3(64, 6), 256, 0, stream>>>(
            h, qkv_w, qkv_b, qkv, 8192, 768, 256, vT);
        attn_kernel<<<dim3(16, 128), 256, 0, stream>>>(qkv, vT, aoutb);
        gemm_bt<128, 64, 32, 64, false><<<dim3(64, 4), 256, 0, stream>>>(
            aoutb, out_w, out_b, projo, 8192, 256, 256, vT);
        ln_kernel<<<2048, 256, 0, stream>>>(h, projo, ln1_s, ln1_b);

        // routing (atomic-free counting sort)
        gate_kernel<<<64, 256, 0, stream>>>(h, gate_w, gate_b,
                                            top_e, top_w, g_hist, auxs + l * 8);
        route_build_kernel<<<1, 256, 0, stream>>>(g_hist, boff, ntiles, tileex, list, lw);
        scatter_kernel<<<64, 256, 0, stream>>>(top_e, top_w, boff, list, lw);

        // top-2 expert FFN (slot 0 covers every token: write; slot 1: accumulate)
        for (int slot = 0; slot < 2; slot++) {
            gemm_moe<128, 128, 64, 64, 1><<<dim3(71, 8), 256, 0, stream>>>(
                h, e_w1, e_b1, hid, 1024, 256,
                list + slot * 9216, lw + slot * 9216, tileex + slot * 72, ntiles + slot);
            if (slot == 0)
                gemm_moe<128, 64, 32, 64, 2><<<dim3(71, 4), 256, 0, stream>>>(
                    hid, e_w2, e_b2, moe, 256, 1024,
                    list, lw, tileex, ntiles);
            else
                gemm_moe<128, 64, 32, 64, 3><<<dim3(71, 4), 256, 0, stream>>>(
                    hid, e_w2, e_b2, moe, 256, 1024,
                    list + 9216, lw + 9216, tileex + 72, ntiles + 1);
        }
        ln_kernel<<<2048, 256, 0, stream>>>(h, moe, ln2_s, ln2_b);
    }

    gemm_bt<128, 128, 64, 64, true><<<dim3(64, 6), 256, 0, stream>>>(
        h, pqkv_w, pqkv_b, qkv, 8192, 768, 256, vT);
    pooled_attn_kernel<<<32, 256, 0, stream>>>(qkv, vT, pattn);
    pooled_proj_kernel<<<16, 256, 0, stream>>>(pattn, pout_w, pout_b, pooled);

    heads_kernel<<<16, 256, 0, stream>>>(
        pooled,
        a_w1, a_b1, a_ln1s, a_ln1b, a_w2, a_b2, a_ln2s, a_ln2b, a_w3, a_b3,
        pr_w1, pr_b1, pr_ln1s, pr_ln1b, pr_w2, pr_b2, pr_ln2s, pr_ln2b, pr_w3, pr_b3,
        ostage);
    aux_kernel<<<1, 64, 0, stream>>>(auxs, ostage);
    out_convert_kernel<<<1, 128, 0, stream>>>(ostage, d_out, flag);
}

// Round 6
// 1202.452 us; speedup vs baseline: 2.3412x; 1.1703x over previous
//
#include <hip/hip_runtime.h>
#include <hip/hip_bf16.h>
#include <math.h>

// ---------------------------------------------------------------------------
// MoE trading transformer forward, MI355X/gfx950.
// B=16 S=512 F_IN=46 D=256 H=8 (dh=32) L=6 E=8 DFF=1024 OUT=3.
// R6: (a) all GEMMs stage via __builtin_amdgcn_global_load_lds width=16 with
// XOR-swizzled LDS chunks (chunk' = chunk ^ (row&7)) -> ds_read_b128 frags
// are 2-way-aliased only (free, m136) while honoring the wave-uniform-base
// +lane*16 LDS constraint; (b) launch fusion: ln1+gate, route+scatter,
// w1 slot0+slot1 (separate hid buffers). 12 -> 9 dispatches/layer.
// ws = 256 MiB (poison fill WRITE_SIZE); layout uses ~123 MB.
// ---------------------------------------------------------------------------

typedef __bf16 bf16;
typedef __bf16 bf16x8 __attribute__((ext_vector_type(8)));
typedef __bf16 bf16x4 __attribute__((ext_vector_type(4)));
typedef float f32x4 __attribute__((ext_vector_type(4)));

#define NIN 41

#define GLOAD_LDS(g, l)                                                    \
    __builtin_amdgcn_global_load_lds(                                      \
        (const __attribute__((address_space(1))) void*)(g),                \
        (__attribute__((address_space(3))) void*)(l), 16, 0, 0)

struct InTab {
    const void* src[NIN];
    unsigned off[NIN];
    unsigned n[NIN];
};

__device__ __forceinline__ float gelu_exact(float x) {
    return 0.5f * x * (1.0f + erff(x * 0.70710678118654752f));
}

// ---------------------------------------------------------------------------
// Dtype sniffer (f32 vs bf16 storage). flag: 1=bf16, 0=f32.
// ---------------------------------------------------------------------------
__global__ void sniff_kernel(const unsigned* __restrict__ xw, int* __restrict__ flag) {
    __shared__ int cnt;
    if (threadIdx.x == 0) cnt = 0;
    __syncthreads();
    const unsigned w = xw[threadIdx.x];
    const unsigned ex = (w >> 7) & 0xFFu;
    if (ex >= 107u && ex <= 133u) atomicAdd(&cnt, 1);
    __syncthreads();
    if (threadIdx.x == 0) *flag = (cnt >= 192) ? 1 : 0;
}

__global__ __launch_bounds__(256) void convert_kernel(
    InTab tab, bf16* __restrict__ dst_base, const int* __restrict__ flag) {
    const unsigned g0 = blockIdx.x * 1024u;
    int inp = 0;
#pragma unroll
    for (int i = 1; i < NIN; i++)
        if (g0 >= tab.off[i]) inp = i;
    const unsigned n = tab.n[inp];
    const unsigned i0 = g0 - tab.off[inp] + threadIdx.x * 4u;
    if (i0 >= n) return;
    const int isbf = *flag;
    bf16* dst = dst_base + tab.off[inp];
    const unsigned end = (i0 + 4u > n) ? n : i0 + 4u;
    if (isbf) {
        const unsigned short* s = (const unsigned short*)tab.src[inp];
        for (unsigned i = i0; i < end; i++) ((unsigned short*)dst)[i] = s[i];
    } else {
        const float* s = (const float*)tab.src[inp];
        for (unsigned i = i0; i < end; i++) dst[i] = (bf16)s[i];
    }
}

__global__ void out_convert_kernel(const float* __restrict__ st, void* __restrict__ out,
                                   const int* __restrict__ flag) {
    const int i = threadIdx.x;
    if (i >= 65) return;
    if (*flag) ((bf16*)out)[i] = (bf16)st[i];
    else       ((float*)out)[i] = st[i];
}

// swizzled LDS element index for (tile-local row r, col-chunk c) [chunks of 8 bf16]
#define SWZ(r, c) (((r) * 8 + ((c) ^ ((r) & 7))) * 8)

// ---------------------------------------------------------------------------
// Dense MFMA GEMM, async-staged + swizzled:  C = A @ W^T + bias.
// VTOUT: cols gn>=512 go transposed to vT[b][h][d][s].
// ---------------------------------------------------------------------------
template <int BM, int BN, int WM, int WN, bool VTOUT>
__global__ __launch_bounds__(256) void gemm_bt(
    const bf16* __restrict__ A, const bf16* __restrict__ W,
    const bf16* __restrict__ bias, bf16* __restrict__ C,
    int M, int N, int K, bf16* __restrict__ vT) {
    constexpr int BK = 64;
    __shared__ alignas(16) bf16 As[BM * BK];
    __shared__ alignas(16) bf16 Ws[BN * BK];
    const int bm0 = blockIdx.x * BM, bn0 = blockIdx.y * BN;
    const int tid = threadIdx.x;
    const int wave = tid >> 6, lane = tid & 63;
    constexpr int WCOLS = BN / WN;
    const int wm0 = (wave / WCOLS) * WM, wn0 = (wave % WCOLS) * WN;
    constexpr int MT = WM / 16, NT = WN / 16;
    f32x4 acc[MT][NT] = {};
    const int frow = lane & 15, fquad = lane >> 4;

    constexpr int AIT = BM / 32, BIT = BN / 32;
    const bf16* ag[AIT];
    const bf16* bg[BIT];
    unsigned al[AIT], bl[BIT];
#pragma unroll
    for (int i = 0; i < AIT; i++) {
        const int d = wave * (BM * 2) + i * 64 + lane;
        const int r = d >> 3, c = ((d & 7) ^ (r & 7)) * 8;
        ag[i] = A + (size_t)(bm0 + r) * K + c;
        al[i] = (unsigned)(wave * (BM * 2) + i * 64) * 8u;
    }
#pragma unroll
    for (int i = 0; i < BIT; i++) {
        const int d = wave * (BN * 2) + i * 64 + lane;
        const int r = d >> 3, c = ((d & 7) ^ (r & 7)) * 8;
        bg[i] = W + (size_t)(bn0 + r) * K + c;
        bl[i] = (unsigned)(wave * (BN * 2) + i * 64) * 8u;
    }

    for (int k0 = 0; k0 < K; k0 += BK) {
#pragma unroll
        for (int i = 0; i < AIT; i++) GLOAD_LDS(ag[i] + k0, &As[al[i]]);
#pragma unroll
        for (int i = 0; i < BIT; i++) GLOAD_LDS(bg[i] + k0, &Ws[bl[i]]);
        __syncthreads();
#pragma unroll
        for (int ks = 0; ks < BK / 32; ks++) {
            bf16x8 af[MT], bfr[NT];
#pragma unroll
            for (int mt = 0; mt < MT; mt++) {
                const int r = wm0 + mt * 16 + frow;
                af[mt] = *(const bf16x8*)&As[SWZ(r, ks * 4 + fquad)];
            }
#pragma unroll
            for (int nt = 0; nt < NT; nt++) {
                const int r = wn0 + nt * 16 + frow;
                bfr[nt] = *(const bf16x8*)&Ws[SWZ(r, ks * 4 + fquad)];
            }
#pragma unroll
            for (int mt = 0; mt < MT; mt++)
#pragma unroll
                for (int nt = 0; nt < NT; nt++)
                    acc[mt][nt] = __builtin_amdgcn_mfma_f32_16x16x32_bf16(
                        af[mt], bfr[nt], acc[mt][nt], 0, 0, 0);
        }
        __syncthreads();
    }

#pragma unroll
    for (int mt = 0; mt < MT; mt++)
#pragma unroll
        for (int nt = 0; nt < NT; nt++) {
            const int gn = bn0 + wn0 + nt * 16 + frow;
            const float bv = (float)bias[gn];
#pragma unroll
            for (int r = 0; r < 4; r++) {
                const int gm = bm0 + wm0 + mt * 16 + fquad * 4 + r;
                const float v = acc[mt][nt][r] + bv;
                if (VTOUT && gn >= 512) {
                    const int d = gn - 512;
                    const int bb = gm >> 9, s = gm & 511;
                    vT[((size_t)(bb * 8 + (d >> 5)) * 32 + (d & 31)) * 512 + s] = (bf16)v;
                } else {
                    C[(size_t)gm * N + gn] = (bf16)v;
                }
            }
        }
}

// ---------------------------------------------------------------------------
// MoE w1 (both slots, one launch): hid{slot}[i] = GELU(h[list[i]] @ w1_e^T + b1_e)
// grid (142, 8): blocks [0,71) slot0, [71,142) slot1.
// ---------------------------------------------------------------------------
__global__ __launch_bounds__(256) void gemm_moe_w1(
    const bf16* __restrict__ A, const bf16* __restrict__ Wb,
    const bf16* __restrict__ biasb, bf16* __restrict__ hid0,
    bf16* __restrict__ hid1, const int* __restrict__ list,
    const int* __restrict__ tile_ex, const int* __restrict__ ntiles) {
    constexpr int BM = 128, BN = 128, BK = 64, WM = 64, WN = 64;
    constexpr int N = 1024, K = 256;
    const int slot = (blockIdx.x >= 71) ? 1 : 0;
    const int xi = blockIdx.x - slot * 71;
    if (xi >= ntiles[slot]) return;
    __shared__ alignas(16) bf16 As[BM * BK];
    __shared__ alignas(16) bf16 Ws[BN * BK];
    const int* mylist = list + slot * 9216;
    const int e = tile_ex[slot * 72 + xi];
    const bf16* W = Wb + (size_t)e * N * K;
    const bf16* bias = biasb + e * N;
    bf16* C = slot ? hid1 : hid0;
    const int bm0 = xi * BM, bn0 = blockIdx.y * BN;
    const int tid = threadIdx.x;
    const int wave = tid >> 6, lane = tid & 63;
    constexpr int WCOLS = BN / WN;
    const int wm0 = (wave / WCOLS) * WM, wn0 = (wave % WCOLS) * WN;
    constexpr int MT = WM / 16, NT = WN / 16;
    f32x4 acc[MT][NT] = {};
    const int frow = lane & 15, fquad = lane >> 4;

    const bf16* ag[4];
    const bf16* bg[4];
    unsigned al[4], bl[4];
#pragma unroll
    for (int i = 0; i < 4; i++) {
        const int d = wave * 256 + i * 64 + lane;
        const int r = d >> 3, c = ((d & 7) ^ (r & 7)) * 8;
        ag[i] = A + (size_t)mylist[bm0 + r] * K + c;
        al[i] = (unsigned)(wave * 256 + i * 64) * 8u;
        bg[i] = W + (size_t)(bn0 + r) * K + c;
        bl[i] = al[i];
    }

    for (int k0 = 0; k0 < K; k0 += BK) {
#pragma unroll
        for (int i = 0; i < 4; i++) GLOAD_LDS(ag[i] + k0, &As[al[i]]);
#pragma unroll
        for (int i = 0; i < 4; i++) GLOAD_LDS(bg[i] + k0, &Ws[bl[i]]);
        __syncthreads();
#pragma unroll
        for (int ks = 0; ks < 2; ks++) {
            bf16x8 af[MT], bfr[NT];
#pragma unroll
            for (int mt = 0; mt < MT; mt++) {
                const int r = wm0 + mt * 16 + frow;
                af[mt] = *(const bf16x8*)&As[SWZ(r, ks * 4 + fquad)];
            }
#pragma unroll
            for (int nt = 0; nt < NT; nt++) {
                const int r = wn0 + nt * 16 + frow;
                bfr[nt] = *(const bf16x8*)&Ws[SWZ(r, ks * 4 + fquad)];
            }
#pragma unroll
            for (int mt = 0; mt < MT; mt++)
#pragma unroll
                for (int nt = 0; nt < NT; nt++)
                    acc[mt][nt] = __builtin_amdgcn_mfma_f32_16x16x32_bf16(
                        af[mt], bfr[nt], acc[mt][nt], 0, 0, 0);
        }
        __syncthreads();
    }

#pragma unroll
    for (int mt = 0; mt < MT; mt++)
#pragma unroll
        for (int nt = 0; nt < NT; nt++) {
            const int gn = bn0 + wn0 + nt * 16 + frow;
            const float bv = (float)bias[gn];
#pragma unroll
            for (int r = 0; r < 4; r++) {
                const int gm = bm0 + wm0 + mt * 16 + fquad * 4 + r;
                C[(size_t)gm * N + gn] = (bf16)gelu_exact(acc[mt][nt][r] + bv);
            }
        }
}

// ---------------------------------------------------------------------------
// MoE w2 over one slot: moe[list[i]] (=|+=) lw[i]*(hid[i] @ w2_e^T + b2_e)
// MODE 2: write, MODE 3: accumulate. grid (71,4), BM=128,BN=64,K=1024.
// ---------------------------------------------------------------------------
template <int MODE>
__global__ __launch_bounds__(256) void gemm_moe_w2(
    const bf16* __restrict__ A, const bf16* __restrict__ Wb,
    const bf16* __restrict__ biasb, bf16* __restrict__ C,
    const int* __restrict__ list, const float* __restrict__ lw,
    const int* __restrict__ tile_ex, const int* __restrict__ ntiles) {
    constexpr int BM = 128, BN = 64, BK = 64, WM = 32, WN = 64;
    constexpr int N = 256, K = 1024;
    if ((int)blockIdx.x >= *ntiles) return;
    __shared__ alignas(16) bf16 As[BM * BK];
    __shared__ alignas(16) bf16 Ws[BN * BK];
    const int e = tile_ex[blockIdx.x];
    const bf16* W = Wb + (size_t)e * N * K;
    const bf16* bias = biasb + e * N;
    const int bm0 = blockIdx.x * BM, bn0 = blockIdx.y * BN;
    const int tid = threadIdx.x;
    const int wave = tid >> 6, lane = tid & 63;
    const int wm0 = wave * WM, wn0 = 0;
    constexpr int MT = WM / 16, NT = WN / 16;
    f32x4 acc[MT][NT] = {};
    const int frow = lane & 15, fquad = lane >> 4;

    const bf16* ag[4];
    const bf16* bg[2];
    unsigned al[4], bl[2];
#pragma unroll
    for (int i = 0; i < 4; i++) {
        const int d = wave * 256 + i * 64 + lane;
        const int r = d >> 3, c = ((d & 7) ^ (r & 7)) * 8;
        ag[i] = A + (size_t)(bm0 + r) * K + c;
        al[i] = (unsigned)(wave * 256 + i * 64) * 8u;
    }
#pragma unroll
    for (int i = 0; i < 2; i++) {
        const int d = wave * 128 + i * 64 + lane;
        const int r = d >> 3, c = ((d & 7) ^ (r & 7)) * 8;
        bg[i] = W + (size_t)(bn0 + r) * K + c;
        bl[i] = (unsigned)(wave * 128 + i * 64) * 8u;
    }

    for (int k0 = 0; k0 < K; k0 += BK) {
#pragma unroll
        for (int i = 0; i < 4; i++) GLOAD_LDS(ag[i] + k0, &As[al[i]]);
#pragma unroll
        for (int i = 0; i < 2; i++) GLOAD_LDS(bg[i] + k0, &Ws[bl[i]]);
        __syncthreads();
#pragma unroll
        for (int ks = 0; ks < 2; ks++) {
            bf16x8 af[MT], bfr[NT];
#pragma unroll
            for (int mt = 0; mt < MT; mt++) {
                const int r = wm0 + mt * 16 + frow;
                af[mt] = *(const bf16x8*)&As[SWZ(r, ks * 4 + fquad)];
            }
#pragma unroll
            for (int nt = 0; nt < NT; nt++) {
                const int r = wn0 + nt * 16 + frow;
                bfr[nt] = *(const bf16x8*)&Ws[SWZ(r, ks * 4 + fquad)];
            }
#pragma unroll
            for (int mt = 0; mt < MT; mt++)
#pragma unroll
                for (int nt = 0; nt < NT; nt++)
                    acc[mt][nt] = __builtin_amdgcn_mfma_f32_16x16x32_bf16(
                        af[mt], bfr[nt], acc[mt][nt], 0, 0, 0);
        }
        __syncthreads();
    }

#pragma unroll
    for (int mt = 0; mt < MT; mt++)
#pragma unroll
        for (int nt = 0; nt < NT; nt++) {
            const int gn = bn0 + wn0 + nt * 16 + frow;
            const float bv = (float)bias[gn];
#pragma unroll
            for (int r = 0; r < 4; r++) {
                const int gm = bm0 + wm0 + mt * 16 + fquad * 4 + r;
                const float v = acc[mt][nt][r] + bv;
                const int token = list[gm];
                const float s = lw[gm];
                bf16* dst = &C[(size_t)token * 256 + gn];
                if (MODE == 2) *dst = (bf16)(s * v);
                else           *dst = (bf16)((float)*dst + s * v);
            }
        }
}

// ---------------------------------------------------------------------------
// Input projection + positional encoding. grid 8192, block 256.
// ---------------------------------------------------------------------------
__global__ __launch_bounds__(256) void input_proj_kernel(
    const bf16* __restrict__ x, const bf16* __restrict__ w,
    const bf16* __restrict__ b, bf16* __restrict__ h) {
    const int m = blockIdx.x, t = threadIdx.x;
    __shared__ float xs[46];
    if (t < 46) xs[t] = (float)x[m * 46 + t];
    __syncthreads();
    float acc = (float)b[t];
#pragma unroll
    for (int k = 0; k < 46; k++) acc += xs[k] * (float)w[t * 46 + k];
    const int s = m & 511;
    const int i = t >> 1;
    const float dv = expf((float)(2 * i) * (-9.210340371976184f / 256.0f));
    const float ang = (float)s * dv;
    const float pe = (t & 1) ? cosf(ang) : sinf(ang);
    h[(size_t)m * 256 + t] = (bf16)(acc + pe);
}

// ---------------------------------------------------------------------------
// Wave-per-token LayerNorm (ln2): h = LN(h+add)*s + b. grid 2048.
// ---------------------------------------------------------------------------
__global__ __launch_bounds__(256) void ln_kernel(
    bf16* __restrict__ h, const bf16* __restrict__ add,
    const bf16* __restrict__ s, const bf16* __restrict__ b) {
    const int m = blockIdx.x * 4 + (threadIdx.x >> 6);
    const int lane = threadIdx.x & 63;
    const int c0 = lane * 4;
    bf16x4 hv = *(const bf16x4*)&h[(size_t)m * 256 + c0];
    bf16x4 av = *(const bf16x4*)&add[(size_t)m * 256 + c0];
    float x[4];
    float s1 = 0.0f, s2 = 0.0f;
#pragma unroll
    for (int j = 0; j < 4; j++) {
        x[j] = (float)hv[j] + (float)av[j];
        s1 += x[j];
        s2 += x[j] * x[j];
    }
#pragma unroll
    for (int msk = 1; msk < 64; msk <<= 1) {
        s1 += __shfl_xor(s1, msk, 64);
        s2 += __shfl_xor(s2, msk, 64);
    }
    const float mean = s1 * (1.0f / 256.0f);
    const float var = fmaxf(s2 * (1.0f / 256.0f) - mean * mean, 0.0f);
    const float inv = rsqrtf(var + 1e-5f);
    bf16x4 sv = *(const bf16x4*)&s[c0];
    bf16x4 bv = *(const bf16x4*)&b[c0];
    bf16x4 o;
#pragma unroll
    for (int j = 0; j < 4; j++)
        o[j] = (bf16)((x[j] - mean) * inv * (float)sv[j] + (float)bv[j]);
    *(bf16x4*)&h[(size_t)m * 256 + c0] = o;
}

// ---------------------------------------------------------------------------
// Fused ln1 + gate: h = LN(h + projo)*s + b (written back), then logits,
// top-2, per-block histogram, aux partials. grid 64 x 256 (128 tokens/blk).
// ---------------------------------------------------------------------------
__global__ __launch_bounds__(256) void gate_ln_kernel(
    bf16* __restrict__ h, const bf16* __restrict__ addv,
    const bf16* __restrict__ lns, const bf16* __restrict__ lnb,
    const bf16* __restrict__ gw, const bf16* __restrict__ gb,
    int* __restrict__ top_e, float* __restrict__ top_w,
    int* __restrict__ g_hist, float* __restrict__ aux_sums) {
    __shared__ alignas(16) bf16 hs[128][264];
    __shared__ alignas(16) bf16 gws[8][264];
    __shared__ float lg[128][9];
    __shared__ float mxs[128], invs[128];
    __shared__ int hist[16];
    const int tid = threadIdx.x;
    {   // stage gate weights
        const int e = tid >> 5, k = (tid & 31) * 8;
        *(bf16x8*)&gws[e][k] = *(const bf16x8*)&gw[e * 256 + k];
    }
    if (tid < 16) hist[tid] = 0;

    // ---- LN: 2 threads per token ----
    const int tl = tid >> 1, half = tid & 1;
    const int tok = blockIdx.x * 128 + tl;
    const int c0 = half * 128;
    float s1 = 0.0f, s2 = 0.0f;
#pragma unroll
    for (int j = 0; j < 128; j += 8) {
        bf16x8 hv = *(const bf16x8*)&h[(size_t)tok * 256 + c0 + j];
        bf16x8 av = *(const bf16x8*)&addv[(size_t)tok * 256 + c0 + j];
        bf16x8 xw;
#pragma unroll
        for (int q = 0; q < 8; q++) {
            const float xq = (float)hv[q] + (float)av[q];
            xw[q] = (bf16)xq;
            s1 += xq;
            s2 += xq * xq;
        }
        *(bf16x8*)&hs[tl][c0 + j] = xw;
    }
    s1 += __shfl_xor(s1, 1, 64);
    s2 += __shfl_xor(s2, 1, 64);
    const float mean = s1 * (1.0f / 256.0f);
    const float var = fmaxf(s2 * (1.0f / 256.0f) - mean * mean, 0.0f);
    const float inv = rsqrtf(var + 1e-5f);
#pragma unroll
    for (int j = 0; j < 128; j += 8) {
        bf16x8 xw = *(const bf16x8*)&hs[tl][c0 + j];
        bf16x8 sv = *(const bf16x8*)&lns[c0 + j];
        bf16x8 bv = *(const bf16x8*)&lnb[c0 + j];
        bf16x8 o;
#pragma unroll
        for (int q = 0; q < 8; q++)
            o[q] = (bf16)(((float)xw[q] - mean) * inv * (float)sv[q] + (float)bv[q]);
        *(bf16x8*)&hs[tl][c0 + j] = o;
        *(bf16x8*)&h[(size_t)tok * 256 + c0 + j] = o;
    }
    __syncthreads();

    // ---- logits from LDS ----
    const int e = tid & 7;
#pragma unroll
    for (int pass = 0; pass < 4; pass++) {
        const int t2 = pass * 32 + (tid >> 3);
        float acc = 0.0f;
        for (int k = 0; k < 256; k += 8) {
            bf16x8 hv = *(const bf16x8*)&hs[t2][k];
            bf16x8 wv = *(const bf16x8*)&gws[e][k];
#pragma unroll
            for (int q = 0; q < 8; q++) acc += (float)hv[q] * (float)wv[q];
        }
        lg[t2][e] = acc + (float)gb[e];
    }
    __syncthreads();

    // ---- top-2 + hist ----
    if (tid < 128) {
        const int t2 = blockIdx.x * 128 + tid;
        float l[8];
#pragma unroll
        for (int j = 0; j < 8; j++) l[j] = lg[tid][j];
        int i0 = 0;
#pragma unroll
        for (int j = 1; j < 8; j++)
            if (l[j] > l[i0]) i0 = j;
        int i1 = -1;
#pragma unroll
        for (int j = 0; j < 8; j++)
            if (j != i0 && (i1 < 0 || l[j] > l[i1])) i1 = j;
        const float p0 = 1.0f / (1.0f + expf(l[i1] - l[i0]));
        top_e[t2] = i0;         top_w[t2] = p0;
        top_e[8192 + t2] = i1;  top_w[8192 + t2] = 1.0f - p0;
        atomicAdd(&hist[i0], 1);
        atomicAdd(&hist[8 + i1], 1);
        const float mx = l[i0];
        float se = 0.0f;
#pragma unroll
        for (int j = 0; j < 8; j++) se += expf(l[j] - mx);
        mxs[tid] = mx;
        invs[tid] = 1.0f / se;
    }
    __syncthreads();
    if (tid < 8) {
        float s = 0.0f;
        for (int t = 0; t < 128; t++) s += expf(lg[t][tid] - mxs[t]) * invs[t];
        atomicAdd(&aux_sums[tid], s);
    }
    if (tid < 16) g_hist[blockIdx.x * 16 + tid] = hist[tid];
}

// ---------------------------------------------------------------------------
// Merged route-build + scatter. grid 64 x 256. Each block recomputes the
// prefix sums from g_hist (4 KB, redundant); block 0 also writes ntiles,
// tile_ex and pad-fills segment tails.
// ---------------------------------------------------------------------------
__global__ __launch_bounds__(256) void scatter_route_kernel(
    const int* __restrict__ g_hist, const int* __restrict__ top_e,
    const float* __restrict__ top_w, int* __restrict__ ntiles,
    int* __restrict__ tile_ex, int* __restrict__ list, float* __restrict__ lw) {
    __shared__ int gh[64][16];
    __shared__ int s_cnt[16], s_pre[16], s_off[16], pos[16];
    const int tid = threadIdx.x;
    for (int i = tid; i < 1024; i += 256) gh[i >> 4][i & 15] = g_hist[i];
    __syncthreads();
    if (tid < 16) {
        int run = 0, pre = 0;
        for (int b = 0; b < 64; b++) {
            if (b == (int)blockIdx.x) pre = run;
            run += gh[b][tid];
        }
        s_cnt[tid] = run;
        s_pre[tid] = pre;
    }
    __syncthreads();
    if (tid < 2) {
        const int slot = tid;
        int o = 0;
        for (int e2 = 0; e2 < 8; e2++) {
            s_off[slot * 8 + e2] = o;
            const int nt = (s_cnt[slot * 8 + e2] + 127) >> 7;
            if (blockIdx.x == 0)
                for (int t = 0; t < nt; t++) tile_ex[slot * 72 + (o >> 7) + t] = e2;
            o += nt << 7;
        }
        if (blockIdx.x == 0) ntiles[slot] = o >> 7;
    }
    __syncthreads();
    if (tid < 16) pos[tid] = s_off[tid] + s_pre[tid];
    __syncthreads();
    if (blockIdx.x == 0) {
        for (int idx = tid; idx < 16 * 128; idx += 256) {
            const int seg = idx >> 7, i = idx & 127;
            const int slot = seg >> 3;
            const int start = s_off[seg] + s_cnt[seg];
            const int end = s_off[seg] + ((s_cnt[seg] + 127) & ~127);
            const int p = start + i;
            if (p < end) {
                list[slot * 9216 + p] = 8192;
                lw[slot * 9216 + p] = 0.0f;
            }
        }
    }
    if (tid < 128) {
        const int tok = blockIdx.x * 128 + tid;
#pragma unroll
        for (int slot = 0; slot < 2; slot++) {
            const int e = top_e[slot * 8192 + tok];
            const float w = top_w[slot * 8192 + tok];
            const int idx = atomicAdd(&pos[slot * 8 + e], 1);
            list[slot * 9216 + idx] = tok;
            lw[slot * 9216 + idx] = w;
        }
    }
}

// ---------------------------------------------------------------------------
// Fused attention, one (b,h) x 32-query tile per block. grid (16,128).
// ---------------------------------------------------------------------------
__global__ __launch_bounds__(256) void attn_kernel(
    const bf16* __restrict__ qkv, const bf16* __restrict__ vT,
    bf16* __restrict__ aout) {
    __shared__ alignas(16) bf16 P[32][520];
    __shared__ float sinv[32];
    const int s0 = blockIdx.x * 32;
    const int b = blockIdx.y >> 3, hh = blockIdx.y & 7;
    const int tid = threadIdx.x, wave = tid >> 6, lane = tid & 63;
    const int frow = lane & 15, fquad = lane >> 4;
    const size_t base = (size_t)b * 512;
    const float scale = 0.17677669529663687f;  // 1/sqrt(32)

    bf16x8 qf[2];
#pragma unroll
    for (int mt = 0; mt < 2; mt++)
        qf[mt] = *(const bf16x8*)&qkv[(base + s0 + mt * 16 + frow) * 768 + hh * 32 + fquad * 8];
#pragma unroll
    for (int k8 = 0; k8 < 8; k8++) {
        const int key0 = (wave * 8 + k8) * 16;
        bf16x8 kf = *(const bf16x8*)&qkv[(base + key0 + frow) * 768 + 256 + hh * 32 + fquad * 8];
#pragma unroll
        for (int mt = 0; mt < 2; mt++) {
            f32x4 c = {};
            c = __builtin_amdgcn_mfma_f32_16x16x32_bf16(qf[mt], kf, c, 0, 0, 0);
#pragma unroll
            for (int r = 0; r < 4; r++)
                P[mt * 16 + fquad * 4 + r][key0 + frow] = (bf16)(c[r] * scale);
        }
    }
    __syncthreads();

    {
        const int row = tid >> 3, c0 = tid & 7;
        float mx = -1e30f;
        for (int j = 0; j < 64; j++) mx = fmaxf(mx, (float)P[row][c0 + 8 * j]);
#pragma unroll
        for (int msk = 1; msk < 8; msk <<= 1) mx = fmaxf(mx, __shfl_xor(mx, msk, 64));
        float se = 0.0f;
        for (int j = 0; j < 64; j++) {
            const float e_ = expf((float)P[row][c0 + 8 * j] - mx);
            se += e_;
            P[row][c0 + 8 * j] = (bf16)e_;
        }
#pragma unroll
        for (int msk = 1; msk < 8; msk <<= 1) se += __shfl_xor(se, msk, 64);
        if (c0 == 0) sinv[row] = 1.0f / se;
    }
    __syncthreads();

    {
        const int mt = wave >> 1, nt = wave & 1;
        const bf16* vrow = &vT[((size_t)(b * 8 + hh) * 32 + nt * 16 + frow) * 512];
        f32x4 o = {};
#pragma unroll
        for (int ks = 0; ks < 16; ks++) {
            bf16x8 pf = *(const bf16x8*)&P[mt * 16 + frow][ks * 32 + fquad * 8];
            bf16x8 vf = *(const bf16x8*)&vrow[ks * 32 + fquad * 8];
            o = __builtin_amdgcn_mfma_f32_16x16x32_bf16(pf, vf, o, 0, 0, 0);
        }
        const int r0 = mt * 16 + fquad * 4;
#pragma unroll
        for (int r = 0; r < 4; r++)
            aout[(base + s0 + r0 + r) * 256 + hh * 32 + nt * 16 + frow] =
                (bf16)(o[r] * sinv[r0 + r]);
    }
}

// ---------------------------------------------------------------------------
// Pooled attention + projection + heads (unchanged from R5).
// ---------------------------------------------------------------------------
__global__ __launch_bounds__(256) void pooled_attn_kernel(
    const bf16* __restrict__ qkv, const bf16* __restrict__ vT,
    bf16* __restrict__ pa) {
    const int wid = blockIdx.x * 4 + (threadIdx.x >> 6);
    const int lane = threadIdx.x & 63;
    const int b = wid >> 3, hh = wid & 7;
    const size_t base = (size_t)b * 512;
    const float scale = 0.17677669529663687f;
    float q[32];
#pragma unroll
    for (int d = 0; d < 32; d++) q[d] = (float)qkv[(base + 511) * 768 + hh * 32 + d];
    float sc[8];
    float mx = -1e30f;
#pragma unroll
    for (int j = 0; j < 8; j++) {
        const int key = lane + j * 64;
        const bf16* kr = &qkv[(base + key) * 768 + 256 + hh * 32];
        float s = 0.0f;
#pragma unroll
        for (int d = 0; d < 32; d++) s += q[d] * (float)kr[d];
        s *= scale;
        sc[j] = s;
        mx = fmaxf(mx, s);
    }
#pragma unroll
    for (int m = 1; m < 64; m <<= 1) mx = fmaxf(mx, __shfl_xor(mx, m, 64));
    float se = 0.0f;
#pragma unroll
    for (int j = 0; j < 8; j++) { sc[j] = expf(sc[j] - mx); se += sc[j]; }
#pragma unroll
    for (int m = 1; m < 64; m <<= 1) se += __shfl_xor(se, m, 64);
    float o[32] = {};
    const bf16* vb = &vT[(size_t)(b * 8 + hh) * 32 * 512];
#pragma unroll
    for (int d = 0; d < 32; d++) {
        const bf16* vr = vb + (size_t)d * 512;
#pragma unroll
        for (int j = 0; j < 8; j++)
            o[d] += sc[j] * (float)vr[lane + j * 64];
    }
#pragma unroll
    for (int d = 0; d < 32; d++) {
#pragma unroll
        for (int m = 1; m < 64; m <<= 1) o[d] += __shfl_xor(o[d], m, 64);
    }
    if (lane == 0) {
        const float inv = 1.0f / se;
        for (int d = 0; d < 32; d++) pa[b * 256 + hh * 32 + d] = (bf16)(o[d] * inv);
    }
}

__global__ __launch_bounds__(256) void pooled_proj_kernel(
    const bf16* __restrict__ pa, const bf16* __restrict__ w,
    const bf16* __restrict__ bias, bf16* __restrict__ pooled) {
    const int b = blockIdx.x, t = threadIdx.x;
    __shared__ float xs[256];
    xs[t] = (float)pa[b * 256 + t];
    __syncthreads();
    float acc = (float)bias[t];
    for (int k = 0; k < 256; k++) acc += xs[k] * (float)w[t * 256 + k];
    pooled[b * 256 + t] = (bf16)acc;
}

__global__ __launch_bounds__(256) void heads_kernel(
    const bf16* __restrict__ pooled,
    const bf16* __restrict__ aw1, const bf16* __restrict__ ab1,
    const bf16* __restrict__ aln1s, const bf16* __restrict__ aln1b,
    const bf16* __restrict__ aw2, const bf16* __restrict__ ab2,
    const bf16* __restrict__ aln2s, const bf16* __restrict__ aln2b,
    const bf16* __restrict__ aw3, const bf16* __restrict__ ab3,
    const bf16* __restrict__ pw1, const bf16* __restrict__ pb1,
    const bf16* __restrict__ pln1s, const bf16* __restrict__ pln1b,
    const bf16* __restrict__ pw2, const bf16* __restrict__ pb2,
    const bf16* __restrict__ pln2s, const bf16* __restrict__ pln2b,
    const bf16* __restrict__ pw3, const bf16* __restrict__ pb3,
    float* __restrict__ out) {
    const int b = blockIdx.x, t = threadIdx.x;
    __shared__ float pool[256], buf[256], buf2[256], r1[256], r2[256];
    pool[t] = (float)pooled[b * 256 + t];
    __syncthreads();

    auto block_ln = [&](float* v, int W, const bf16* ls, const bf16* lb) {
        const float val = (t < W) ? v[t] : 0.0f;
        r1[t] = val;
        r2[t] = val * val;
        __syncthreads();
        for (int off = 128; off > 0; off >>= 1) {
            if (t < off) { r1[t] += r1[t + off]; r2[t] += r2[t + off]; }
            __syncthreads();
        }
        const float mean = r1[0] / (float)W;
        const float var = fmaxf(r2[0] / (float)W - mean * mean, 0.0f);
        const float inv = rsqrtf(var + 1e-5f);
        __syncthreads();
        if (t < W) v[t] = (val - mean) * inv * (float)ls[t] + (float)lb[t];
        __syncthreads();
    };

    float a;
    if (t < 128) {
        a = (float)ab1[t];
        for (int k = 0; k < 256; k++) a += pool[k] * (float)aw1[t * 256 + k];
        buf[t] = gelu_exact(a);
    }
    __syncthreads();
    block_ln(buf, 128, aln1s, aln1b);
    if (t < 64) {
        a = (float)ab2[t];
        for (int k = 0; k < 128; k++) a += buf[k] * (float)aw2[t * 128 + k];
        buf2[t] = gelu_exact(a);
    }
    __syncthreads();
    block_ln(buf2, 64, aln2s, aln2b);
    if (t < 3) {
        a = (float)ab3[t];
        for (int k = 0; k < 64; k++) a += buf2[k] * (float)aw3[t * 64 + k];
        out[b * 3 + t] = a;
    }

    a = (float)pb1[t];
    for (int k = 0; k < 256; k++) a += pool[k] * (float)pw1[t * 256 + k];
    buf[t] = a;
    __syncthreads();
    block_ln(buf, 256, pln1s, pln1b);
    buf[t] = gelu_exact(buf[t]);
    __syncthreads();
    if (t < 128) {
        a = (float)pb2[t];
        for (int k = 0; k < 256; k++) a += buf[k] * (float)pw2[t * 256 + k];
        buf2[t] = a;
    }
    __syncthreads();
    block_ln(buf2, 128, pln2s, pln2b);
    if (t < 128) buf2[t] = gelu_exact(buf2[t]);
    __syncthreads();
    if (t == 0) {
        a = (float)pb3[0];
        for (int k = 0; k < 128; k++) a += buf2[k] * (float)pw3[k];
        out[48 + b] = a;
    }
}

__global__ void aux_kernel(const float* __restrict__ sums, float* __restrict__ out) {
    if (threadIdx.x == 0 && blockIdx.x == 0) {
        float tot = 0.0f;
        for (int l = 0; l < 6; l++)
            for (int e = 0; e < 8; e++) {
                const float mn = sums[l * 8 + e] * (1.0f / 8192.0f);
                tot += 8.0f * mn * mn;
            }
        out[64] = tot;
    }
}

// ---------------------------------------------------------------------------
extern "C" void kernel_launch(void* const* d_in, const int* in_sizes, int n_in,
                              void* d_out, int out_size, void* d_ws, size_t ws_size,
                              hipStream_t stream) {
    char* ws = (char*)d_ws;
    const size_t MB = 1024 * 1024;
    bf16*  h     = (bf16*)(ws);                        // 8193x256
    bf16*  moe   = (bf16*)(ws + 8 * MB);               // 8193x256
    char*  ctrl  = ws + 16 * MB;
    float* auxs   = (float*)(ctrl + 0);                // 48 f32
    int*   flag   = (int*)(ctrl + 192);
    int*   ntiles = (int*)(ctrl + 256);                // [2]
    int*   tileex = (int*)(ctrl + 320);                // [2][72]
    float* ostage = (float*)(ctrl + 1024);             // 65 f32
    int*   g_hist = (int*)(ctrl + 2048);               // [64][16]
    int*   top_e  = (int*)(ctrl + 10240);              // [2][8192]
    float* top_w  = (float*)(ctrl + 75776);            // [2][8192]
    int*   list   = (int*)(ctrl + 141312);             // [2][9216]
    float* lw     = (float*)(ctrl + 215040);           // [2][9216]
    bf16*  qkv   = (bf16*)(ws + 24 * MB);              // 8192x768
    bf16*  aoutb = (bf16*)(ws + 40 * MB);              // 8192x256
    bf16*  projo = (bf16*)(ws + 48 * MB);              // 8192x256
    bf16*  hid0  = (bf16*)(ws + 56 * MB);              // 9216x1024
    bf16*  hid1  = (bf16*)(ws + 80 * MB);              // 9216x1024
    bf16*  vT    = (bf16*)(ws + 104 * MB);             // [16][8][32][512]
    bf16*  pattn  = (bf16*)(ws + 110 * MB);
    bf16*  pooled = (bf16*)(ws + 110 * MB + 8192);
    bf16*  cvbase = (bf16*)(ws + 112 * MB);            // ~10.6 MB

    InTab tab;
    unsigned off = 0;
    bf16* cv[NIN];
    for (int i = 0; i < NIN; i++) {
        tab.src[i] = d_in[i];
        tab.off[i] = off;
        tab.n[i] = (unsigned)in_sizes[i];
        cv[i] = cvbase + off;
        off += ((unsigned)in_sizes[i] + 1023u) & ~1023u;
    }
    const int cv_blocks = (int)(off >> 10);

    const bf16 *x = cv[0], *in_w = cv[1], *in_b = cv[2], *qkv_w = cv[3], *qkv_b = cv[4],
               *out_w = cv[5], *out_b = cv[6], *gate_w = cv[7], *gate_b = cv[8],
               *e_w1 = cv[9], *e_b1 = cv[10], *e_w2 = cv[11], *e_b2 = cv[12],
               *ln1_s = cv[13], *ln1_b = cv[14], *ln2_s = cv[15], *ln2_b = cv[16],
               *pqkv_w = cv[17], *pqkv_b = cv[18], *pout_w = cv[19], *pout_b = cv[20],
               *a_w1 = cv[21], *a_b1 = cv[22], *a_ln1s = cv[23], *a_ln1b = cv[24],
               *a_w2 = cv[25], *a_b2 = cv[26], *a_ln2s = cv[27], *a_ln2b = cv[28],
               *a_w3 = cv[29], *a_b3 = cv[30],
               *pr_w1 = cv[31], *pr_b1 = cv[32], *pr_ln1s = cv[33], *pr_ln1b = cv[34],
               *pr_w2 = cv[35], *pr_b2 = cv[36], *pr_ln2s = cv[37], *pr_ln2b = cv[38],
               *pr_w3 = cv[39], *pr_b3 = cv[40];

    sniff_kernel<<<1, 256, 0, stream>>>((const unsigned*)d_in[0], flag);
    convert_kernel<<<cv_blocks, 256, 0, stream>>>(tab, cvbase, flag);

    hipMemsetAsync(auxs, 0, 192, stream);
    input_proj_kernel<<<8192, 256, 0, stream>>>(x, in_w, in_b, h);

    for (int l = 0; l < 6; l++) {
        gemm_bt<128, 128, 64, 64, true><<<dim3(64, 6), 256, 0, stream>>>(
            h, qkv_w, qkv_b, qkv, 8192, 768, 256, vT);
        attn_kernel<<<dim3(16, 128), 256, 0, stream>>>(qkv, vT, aoutb);
        gemm_bt<128, 64, 32, 64, false><<<dim3(64, 4), 256, 0, stream>>>(
            aoutb, out_w, out_b, projo, 8192, 256, 256, vT);
        gate_ln_kernel<<<64, 256, 0, stream>>>(h, projo, ln1_s, ln1_b,
                                               gate_w, gate_b,
                                               top_e, top_w, g_hist, auxs + l * 8);
        scatter_route_kernel<<<64, 256, 0, stream>>>(g_hist, top_e, top_w,
                                                     ntiles, tileex, list, lw);
        gemm_moe_w1<<<dim3(142, 8), 256, 0, stream>>>(
            h, e_w1, e_b1, hid0, hid1, list, tileex, ntiles);
        gemm_moe_w2<2><<<dim3(71, 4), 256, 0, stream>>>(
            hid0, e_w2, e_b2, moe, list, lw, tileex, ntiles);
        gemm_moe_w2<3><<<dim3(71, 4), 256, 0, stream>>>(
            hid1, e_w2, e_b2, moe, list + 9216, lw + 9216, tileex + 72, ntiles + 1);
        ln_kernel<<<2048, 256, 0, stream>>>(h, moe, ln2_s, ln2_b);
    }

    gemm_bt<128, 128, 64, 64, true><<<dim3(64, 6), 256, 0, stream>>>(
        h, pqkv_w, pqkv_b, qkv, 8192, 768, 256, vT);
    pooled_attn_kernel<<<32, 256, 0, stream>>>(qkv, vT, pattn);
    pooled_proj_kernel<<<16, 256, 0, stream>>>(pattn, pout_w, pout_b, pooled);

    heads_kernel<<<16, 256, 0, stream>>>(
        pooled,
        a_w1, a_b1, a_ln1s, a_ln1b, a_w2, a_b2, a_ln2s, a_ln2b, a_w3, a_b3,
        pr_w1, pr_b1, pr_ln1s, pr_ln1b, pr_w2, pr_b2, pr_ln2s, pr_ln2b, pr_w3, pr_b3,
        ostage);
    aux_kernel<<<1, 64, 0, stream>>>(auxs, ostage);
    out_convert_kernel<<<1, 128, 0, stream>>>(ostage, d_out, flag);
}

// Round 7
// 1085.743 us; speedup vs baseline: 2.5929x; 1.1075x over previous
//
#include <hip/hip_runtime.h>
#include <hip/hip_bf16.h>
#include <math.h>

// ---------------------------------------------------------------------------
// MoE trading transformer forward, MI355X/gfx950.
// B=16 S=512 F_IN=46 D=256 H=8 (dh=32) L=6 E=8 DFF=1024 OUT=3.
// R7: (a) attention: exp folded into QK MFMA epilogue (register exp2f),
// per-wave shuffle row-sums -> zero softmax LDS sweeps, 2 barriers total;
// (b) w2 slots merged into one launch writing disjoint moe0/moe1 (ln2 adds
// both) -> no w2a->w2b serialization; (c) dense GEMMs BM=64 tiles for
// 2-3 blocks/CU latency overlap. 8 dispatches/layer.
// ws = 256 MiB; layout uses ~123 MB.
// ---------------------------------------------------------------------------

typedef __bf16 bf16;
typedef __bf16 bf16x8 __attribute__((ext_vector_type(8)));
typedef __bf16 bf16x4 __attribute__((ext_vector_type(4)));
typedef float f32x4 __attribute__((ext_vector_type(4)));

#define NIN 41

#define GLOAD_LDS(g, l)                                                    \
    __builtin_amdgcn_global_load_lds(                                      \
        (const __attribute__((address_space(1))) void*)(g),                \
        (__attribute__((address_space(3))) void*)(l), 16, 0, 0)

struct InTab {
    const void* src[NIN];
    unsigned off[NIN];
    unsigned n[NIN];
};

__device__ __forceinline__ float gelu_exact(float x) {
    return 0.5f * x * (1.0f + erff(x * 0.70710678118654752f));
}

// ---------------------------------------------------------------------------
// Dtype sniffer (f32 vs bf16 storage). flag: 1=bf16, 0=f32.
// ---------------------------------------------------------------------------
__global__ void sniff_kernel(const unsigned* __restrict__ xw, int* __restrict__ flag) {
    __shared__ int cnt;
    if (threadIdx.x == 0) cnt = 0;
    __syncthreads();
    const unsigned w = xw[threadIdx.x];
    const unsigned ex = (w >> 7) & 0xFFu;
    if (ex >= 107u && ex <= 133u) atomicAdd(&cnt, 1);
    __syncthreads();
    if (threadIdx.x == 0) *flag = (cnt >= 192) ? 1 : 0;
}

__global__ __launch_bounds__(256) void convert_kernel(
    InTab tab, bf16* __restrict__ dst_base, const int* __restrict__ flag) {
    const unsigned g0 = blockIdx.x * 1024u;
    int inp = 0;
#pragma unroll
    for (int i = 1; i < NIN; i++)
        if (g0 >= tab.off[i]) inp = i;
    const unsigned n = tab.n[inp];
    const unsigned i0 = g0 - tab.off[inp] + threadIdx.x * 4u;
    if (i0 >= n) return;
    const int isbf = *flag;
    bf16* dst = dst_base + tab.off[inp];
    const unsigned end = (i0 + 4u > n) ? n : i0 + 4u;
    if (isbf) {
        const unsigned short* s = (const unsigned short*)tab.src[inp];
        for (unsigned i = i0; i < end; i++) ((unsigned short*)dst)[i] = s[i];
    } else {
        const float* s = (const float*)tab.src[inp];
        for (unsigned i = i0; i < end; i++) dst[i] = (bf16)s[i];
    }
}

__global__ void out_convert_kernel(const float* __restrict__ st, void* __restrict__ out,
                                   const int* __restrict__ flag) {
    const int i = threadIdx.x;
    if (i >= 65) return;
    if (*flag) ((bf16*)out)[i] = (bf16)st[i];
    else       ((float*)out)[i] = st[i];
}

// swizzled LDS element index for (tile-local row r, col-chunk c) [chunks of 8 bf16]
#define SWZ(r, c) (((r) * 8 + ((c) ^ ((r) & 7))) * 8)

// ---------------------------------------------------------------------------
// Dense MFMA GEMM, async-staged + swizzled:  C = A @ W^T + bias.
// VTOUT: cols gn>=512 go transposed to vT[b][h][d][s].
// ---------------------------------------------------------------------------
template <int BM, int BN, int WM, int WN, bool VTOUT>
__global__ __launch_bounds__(256) void gemm_bt(
    const bf16* __restrict__ A, const bf16* __restrict__ W,
    const bf16* __restrict__ bias, bf16* __restrict__ C,
    int M, int N, int K, bf16* __restrict__ vT) {
    constexpr int BK = 64;
    __shared__ alignas(16) bf16 As[BM * BK];
    __shared__ alignas(16) bf16 Ws[BN * BK];
    const int bm0 = blockIdx.x * BM, bn0 = blockIdx.y * BN;
    const int tid = threadIdx.x;
    const int wave = tid >> 6, lane = tid & 63;
    constexpr int WCOLS = BN / WN;
    const int wm0 = (wave / WCOLS) * WM, wn0 = (wave % WCOLS) * WN;
    constexpr int MT = WM / 16, NT = WN / 16;
    f32x4 acc[MT][NT] = {};
    const int frow = lane & 15, fquad = lane >> 4;

    constexpr int AIT = BM / 32, BIT = BN / 32;
    const bf16* ag[AIT];
    const bf16* bg[BIT];
    unsigned al[AIT], bl[BIT];
#pragma unroll
    for (int i = 0; i < AIT; i++) {
        const int d = wave * (BM * 2) + i * 64 + lane;
        const int r = d >> 3, c = ((d & 7) ^ (r & 7)) * 8;
        ag[i] = A + (size_t)(bm0 + r) * K + c;
        al[i] = (unsigned)(wave * (BM * 2) + i * 64) * 8u;
    }
#pragma unroll
    for (int i = 0; i < BIT; i++) {
        const int d = wave * (BN * 2) + i * 64 + lane;
        const int r = d >> 3, c = ((d & 7) ^ (r & 7)) * 8;
        bg[i] = W + (size_t)(bn0 + r) * K + c;
        bl[i] = (unsigned)(wave * (BN * 2) + i * 64) * 8u;
    }

    for (int k0 = 0; k0 < K; k0 += BK) {
#pragma unroll
        for (int i = 0; i < AIT; i++) GLOAD_LDS(ag[i] + k0, &As[al[i]]);
#pragma unroll
        for (int i = 0; i < BIT; i++) GLOAD_LDS(bg[i] + k0, &Ws[bl[i]]);
        __syncthreads();
#pragma unroll
        for (int ks = 0; ks < BK / 32; ks++) {
            bf16x8 af[MT], bfr[NT];
#pragma unroll
            for (int mt = 0; mt < MT; mt++) {
                const int r = wm0 + mt * 16 + frow;
                af[mt] = *(const bf16x8*)&As[SWZ(r, ks * 4 + fquad)];
            }
#pragma unroll
            for (int nt = 0; nt < NT; nt++) {
                const int r = wn0 + nt * 16 + frow;
                bfr[nt] = *(const bf16x8*)&Ws[SWZ(r, ks * 4 + fquad)];
            }
#pragma unroll
            for (int mt = 0; mt < MT; mt++)
#pragma unroll
                for (int nt = 0; nt < NT; nt++)
                    acc[mt][nt] = __builtin_amdgcn_mfma_f32_16x16x32_bf16(
                        af[mt], bfr[nt], acc[mt][nt], 0, 0, 0);
        }
        __syncthreads();
    }

#pragma unroll
    for (int mt = 0; mt < MT; mt++)
#pragma unroll
        for (int nt = 0; nt < NT; nt++) {
            const int gn = bn0 + wn0 + nt * 16 + frow;
            const float bv = (float)bias[gn];
#pragma unroll
            for (int r = 0; r < 4; r++) {
                const int gm = bm0 + wm0 + mt * 16 + fquad * 4 + r;
                const float v = acc[mt][nt][r] + bv;
                if (VTOUT && gn >= 512) {
                    const int d = gn - 512;
                    const int bb = gm >> 9, s = gm & 511;
                    vT[((size_t)(bb * 8 + (d >> 5)) * 32 + (d & 31)) * 512 + s] = (bf16)v;
                } else {
                    C[(size_t)gm * N + gn] = (bf16)v;
                }
            }
        }
}

// ---------------------------------------------------------------------------
// MoE w1 (both slots, one launch): hid{slot}[i] = GELU(h[list[i]] @ w1_e^T + b1_e)
// grid (142, 8): blocks [0,71) slot0, [71,142) slot1.
// ---------------------------------------------------------------------------
__global__ __launch_bounds__(256) void gemm_moe_w1(
    const bf16* __restrict__ A, const bf16* __restrict__ Wb,
    const bf16* __restrict__ biasb, bf16* __restrict__ hid0,
    bf16* __restrict__ hid1, const int* __restrict__ list,
    const int* __restrict__ tile_ex, const int* __restrict__ ntiles) {
    constexpr int BM = 128, BN = 128, BK = 64, WM = 64, WN = 64;
    constexpr int N = 1024, K = 256;
    const int slot = (blockIdx.x >= 71) ? 1 : 0;
    const int xi = blockIdx.x - slot * 71;
    if (xi >= ntiles[slot]) return;
    __shared__ alignas(16) bf16 As[BM * BK];
    __shared__ alignas(16) bf16 Ws[BN * BK];
    const int* mylist = list + slot * 9216;
    const int e = tile_ex[slot * 72 + xi];
    const bf16* W = Wb + (size_t)e * N * K;
    const bf16* bias = biasb + e * N;
    bf16* C = slot ? hid1 : hid0;
    const int bm0 = xi * BM, bn0 = blockIdx.y * BN;
    const int tid = threadIdx.x;
    const int wave = tid >> 6, lane = tid & 63;
    constexpr int WCOLS = BN / WN;
    const int wm0 = (wave / WCOLS) * WM, wn0 = (wave % WCOLS) * WN;
    constexpr int MT = WM / 16, NT = WN / 16;
    f32x4 acc[MT][NT] = {};
    const int frow = lane & 15, fquad = lane >> 4;

    const bf16* ag[4];
    const bf16* bg[4];
    unsigned al[4], bl[4];
#pragma unroll
    for (int i = 0; i < 4; i++) {
        const int d = wave * 256 + i * 64 + lane;
        const int r = d >> 3, c = ((d & 7) ^ (r & 7)) * 8;
        ag[i] = A + (size_t)mylist[bm0 + r] * K + c;
        al[i] = (unsigned)(wave * 256 + i * 64) * 8u;
        bg[i] = W + (size_t)(bn0 + r) * K + c;
        bl[i] = al[i];
    }

    for (int k0 = 0; k0 < K; k0 += BK) {
#pragma unroll
        for (int i = 0; i < 4; i++) GLOAD_LDS(ag[i] + k0, &As[al[i]]);
#pragma unroll
        for (int i = 0; i < 4; i++) GLOAD_LDS(bg[i] + k0, &Ws[bl[i]]);
        __syncthreads();
#pragma unroll
        for (int ks = 0; ks < 2; ks++) {
            bf16x8 af[MT], bfr[NT];
#pragma unroll
            for (int mt = 0; mt < MT; mt++) {
                const int r = wm0 + mt * 16 + frow;
                af[mt] = *(const bf16x8*)&As[SWZ(r, ks * 4 + fquad)];
            }
#pragma unroll
            for (int nt = 0; nt < NT; nt++) {
                const int r = wn0 + nt * 16 + frow;
                bfr[nt] = *(const bf16x8*)&Ws[SWZ(r, ks * 4 + fquad)];
            }
#pragma unroll
            for (int mt = 0; mt < MT; mt++)
#pragma unroll
                for (int nt = 0; nt < NT; nt++)
                    acc[mt][nt] = __builtin_amdgcn_mfma_f32_16x16x32_bf16(
                        af[mt], bfr[nt], acc[mt][nt], 0, 0, 0);
        }
        __syncthreads();
    }

#pragma unroll
    for (int mt = 0; mt < MT; mt++)
#pragma unroll
        for (int nt = 0; nt < NT; nt++) {
            const int gn = bn0 + wn0 + nt * 16 + frow;
            const float bv = (float)bias[gn];
#pragma unroll
            for (int r = 0; r < 4; r++) {
                const int gm = bm0 + wm0 + mt * 16 + fquad * 4 + r;
                C[(size_t)gm * N + gn] = (bf16)gelu_exact(acc[mt][nt][r] + bv);
            }
        }
}

// ---------------------------------------------------------------------------
// MoE w2, both slots in one launch (disjoint outputs moe0/moe1):
// moe{slot}[list[i]] = lw[i]*(hid{slot}[i] @ w2_e^T + b2_e)
// grid (142, 4): blocks [0,71) slot0, [71,142) slot1.
// ---------------------------------------------------------------------------
__global__ __launch_bounds__(256) void gemm_moe_w2(
    const bf16* __restrict__ hid0, const bf16* __restrict__ hid1,
    const bf16* __restrict__ Wb, const bf16* __restrict__ biasb,
    bf16* __restrict__ moe0, bf16* __restrict__ moe1,
    const int* __restrict__ list, const float* __restrict__ lw,
    const int* __restrict__ tile_ex, const int* __restrict__ ntiles) {
    constexpr int BM = 128, BN = 64, BK = 64, WM = 32;
    constexpr int N = 256, K = 1024;
    const int slot = (blockIdx.x >= 71) ? 1 : 0;
    const int xi = blockIdx.x - slot * 71;
    if (xi >= ntiles[slot]) return;
    __shared__ alignas(16) bf16 As[BM * BK];
    __shared__ alignas(16) bf16 Ws[BN * BK];
    const bf16* A = slot ? hid1 : hid0;
    bf16* C = slot ? moe1 : moe0;
    const int* mylist = list + slot * 9216;
    const float* mylw = lw + slot * 9216;
    const int e = tile_ex[slot * 72 + xi];
    const bf16* W = Wb + (size_t)e * N * K;
    const bf16* bias = biasb + e * N;
    const int bm0 = xi * BM, bn0 = blockIdx.y * BN;
    const int tid = threadIdx.x;
    const int wave = tid >> 6, lane = tid & 63;
    const int wm0 = wave * WM;
    constexpr int MT = WM / 16, NT = 4;
    f32x4 acc[MT][NT] = {};
    const int frow = lane & 15, fquad = lane >> 4;

    const bf16* ag[4];
    const bf16* bg[2];
    unsigned al[4], bl[2];
#pragma unroll
    for (int i = 0; i < 4; i++) {
        const int d = wave * 256 + i * 64 + lane;
        const int r = d >> 3, c = ((d & 7) ^ (r & 7)) * 8;
        ag[i] = A + (size_t)(bm0 + r) * K + c;
        al[i] = (unsigned)(wave * 256 + i * 64) * 8u;
    }
#pragma unroll
    for (int i = 0; i < 2; i++) {
        const int d = wave * 128 + i * 64 + lane;
        const int r = d >> 3, c = ((d & 7) ^ (r & 7)) * 8;
        bg[i] = W + (size_t)(bn0 + r) * K + c;
        bl[i] = (unsigned)(wave * 128 + i * 64) * 8u;
    }

    for (int k0 = 0; k0 < K; k0 += BK) {
#pragma unroll
        for (int i = 0; i < 4; i++) GLOAD_LDS(ag[i] + k0, &As[al[i]]);
#pragma unroll
        for (int i = 0; i < 2; i++) GLOAD_LDS(bg[i] + k0, &Ws[bl[i]]);
        __syncthreads();
#pragma unroll
        for (int ks = 0; ks < 2; ks++) {
            bf16x8 af[MT], bfr[NT];
#pragma unroll
            for (int mt = 0; mt < MT; mt++) {
                const int r = wm0 + mt * 16 + frow;
                af[mt] = *(const bf16x8*)&As[SWZ(r, ks * 4 + fquad)];
            }
#pragma unroll
            for (int nt = 0; nt < NT; nt++) {
                const int r = nt * 16 + frow;
                bfr[nt] = *(const bf16x8*)&Ws[SWZ(r, ks * 4 + fquad)];
            }
#pragma unroll
            for (int mt = 0; mt < MT; mt++)
#pragma unroll
                for (int nt = 0; nt < NT; nt++)
                    acc[mt][nt] = __builtin_amdgcn_mfma_f32_16x16x32_bf16(
                        af[mt], bfr[nt], acc[mt][nt], 0, 0, 0);
        }
        __syncthreads();
    }

#pragma unroll
    for (int mt = 0; mt < MT; mt++)
#pragma unroll
        for (int nt = 0; nt < NT; nt++) {
            const int gn = bn0 + nt * 16 + frow;
            const float bv = (float)bias[gn];
#pragma unroll
            for (int r = 0; r < 4; r++) {
                const int gm = bm0 + wm0 + mt * 16 + fquad * 4 + r;
                const float v = acc[mt][nt][r] + bv;
                C[(size_t)mylist[gm] * 256 + gn] = (bf16)(mylw[gm] * v);
            }
        }
}

// ---------------------------------------------------------------------------
// Input projection + positional encoding. grid 8192, block 256.
// ---------------------------------------------------------------------------
__global__ __launch_bounds__(256) void input_proj_kernel(
    const bf16* __restrict__ x, const bf16* __restrict__ w,
    const bf16* __restrict__ b, bf16* __restrict__ h) {
    const int m = blockIdx.x, t = threadIdx.x;
    __shared__ float xs[46];
    if (t < 46) xs[t] = (float)x[m * 46 + t];
    __syncthreads();
    float acc = (float)b[t];
#pragma unroll
    for (int k = 0; k < 46; k++) acc += xs[k] * (float)w[t * 46 + k];
    const int s = m & 511;
    const int i = t >> 1;
    const float dv = expf((float)(2 * i) * (-9.210340371976184f / 256.0f));
    const float ang = (float)s * dv;
    const float pe = (t & 1) ? cosf(ang) : sinf(ang);
    h[(size_t)m * 256 + t] = (bf16)(acc + pe);
}

// ---------------------------------------------------------------------------
// Wave-per-token LayerNorm (ln2): h = LN(h + a0 + a1)*s + b. grid 2048.
// ---------------------------------------------------------------------------
__global__ __launch_bounds__(256) void ln_kernel(
    bf16* __restrict__ h, const bf16* __restrict__ a0,
    const bf16* __restrict__ a1, const bf16* __restrict__ s,
    const bf16* __restrict__ b) {
    const int m = blockIdx.x * 4 + (threadIdx.x >> 6);
    const int lane = threadIdx.x & 63;
    const int c0 = lane * 4;
    bf16x4 hv = *(const bf16x4*)&h[(size_t)m * 256 + c0];
    bf16x4 av = *(const bf16x4*)&a0[(size_t)m * 256 + c0];
    bf16x4 bv2 = *(const bf16x4*)&a1[(size_t)m * 256 + c0];
    float x[4];
    float s1 = 0.0f, s2 = 0.0f;
#pragma unroll
    for (int j = 0; j < 4; j++) {
        x[j] = (float)hv[j] + (float)av[j] + (float)bv2[j];
        s1 += x[j];
        s2 += x[j] * x[j];
    }
#pragma unroll
    for (int msk = 1; msk < 64; msk <<= 1) {
        s1 += __shfl_xor(s1, msk, 64);
        s2 += __shfl_xor(s2, msk, 64);
    }
    const float mean = s1 * (1.0f / 256.0f);
    const float var = fmaxf(s2 * (1.0f / 256.0f) - mean * mean, 0.0f);
    const float inv = rsqrtf(var + 1e-5f);
    bf16x4 sv = *(const bf16x4*)&s[c0];
    bf16x4 bv = *(const bf16x4*)&b[c0];
    bf16x4 o;
#pragma unroll
    for (int j = 0; j < 4; j++)
        o[j] = (bf16)((x[j] - mean) * inv * (float)sv[j] + (float)bv[j]);
    *(bf16x4*)&h[(size_t)m * 256 + c0] = o;
}

// ---------------------------------------------------------------------------
// Fused ln1 + gate. grid 64 x 256 (128 tokens/blk).
// ---------------------------------------------------------------------------
__global__ __launch_bounds__(256) void gate_ln_kernel(
    bf16* __restrict__ h, const bf16* __restrict__ addv,
    const bf16* __restrict__ lns, const bf16* __restrict__ lnb,
    const bf16* __restrict__ gw, const bf16* __restrict__ gb,
    int* __restrict__ top_e, float* __restrict__ top_w,
    int* __restrict__ g_hist, float* __restrict__ aux_sums) {
    __shared__ alignas(16) bf16 hs[128][264];
    __shared__ alignas(16) bf16 gws[8][264];
    __shared__ float lg[128][9];
    __shared__ float mxs[128], invs[128];
    __shared__ int hist[16];
    const int tid = threadIdx.x;
    {
        const int e = tid >> 5, k = (tid & 31) * 8;
        *(bf16x8*)&gws[e][k] = *(const bf16x8*)&gw[e * 256 + k];
    }
    if (tid < 16) hist[tid] = 0;

    const int tl = tid >> 1, half = tid & 1;
    const int tok = blockIdx.x * 128 + tl;
    const int c0 = half * 128;
    float s1 = 0.0f, s2 = 0.0f;
#pragma unroll
    for (int j = 0; j < 128; j += 8) {
        bf16x8 hv = *(const bf16x8*)&h[(size_t)tok * 256 + c0 + j];
        bf16x8 av = *(const bf16x8*)&addv[(size_t)tok * 256 + c0 + j];
        bf16x8 xw;
#pragma unroll
        for (int q = 0; q < 8; q++) {
            const float xq = (float)hv[q] + (float)av[q];
            xw[q] = (bf16)xq;
            s1 += xq;
            s2 += xq * xq;
        }
        *(bf16x8*)&hs[tl][c0 + j] = xw;
    }
    s1 += __shfl_xor(s1, 1, 64);
    s2 += __shfl_xor(s2, 1, 64);
    const float mean = s1 * (1.0f / 256.0f);
    const float var = fmaxf(s2 * (1.0f / 256.0f) - mean * mean, 0.0f);
    const float inv = rsqrtf(var + 1e-5f);
#pragma unroll
    for (int j = 0; j < 128; j += 8) {
        bf16x8 xw = *(const bf16x8*)&hs[tl][c0 + j];
        bf16x8 sv = *(const bf16x8*)&lns[c0 + j];
        bf16x8 bv = *(const bf16x8*)&lnb[c0 + j];
        bf16x8 o;
#pragma unroll
        for (int q = 0; q < 8; q++)
            o[q] = (bf16)(((float)xw[q] - mean) * inv * (float)sv[q] + (float)bv[q]);
        *(bf16x8*)&hs[tl][c0 + j] = o;
        *(bf16x8*)&h[(size_t)tok * 256 + c0 + j] = o;
    }
    __syncthreads();

    const int e = tid & 7;
#pragma unroll
    for (int pass = 0; pass < 4; pass++) {
        const int t2 = pass * 32 + (tid >> 3);
        float acc = 0.0f;
        for (int k = 0; k < 256; k += 8) {
            bf16x8 hv = *(const bf16x8*)&hs[t2][k];
            bf16x8 wv = *(const bf16x8*)&gws[e][k];
#pragma unroll
            for (int q = 0; q < 8; q++) acc += (float)hv[q] * (float)wv[q];
        }
        lg[t2][e] = acc + (float)gb[e];
    }
    __syncthreads();

    if (tid < 128) {
        const int t2 = blockIdx.x * 128 + tid;
        float l[8];
#pragma unroll
        for (int j = 0; j < 8; j++) l[j] = lg[tid][j];
        int i0 = 0;
#pragma unroll
        for (int j = 1; j < 8; j++)
            if (l[j] > l[i0]) i0 = j;
        int i1 = -1;
#pragma unroll
        for (int j = 0; j < 8; j++)
            if (j != i0 && (i1 < 0 || l[j] > l[i1])) i1 = j;
        const float p0 = 1.0f / (1.0f + expf(l[i1] - l[i0]));
        top_e[t2] = i0;         top_w[t2] = p0;
        top_e[8192 + t2] = i1;  top_w[8192 + t2] = 1.0f - p0;
        atomicAdd(&hist[i0], 1);
        atomicAdd(&hist[8 + i1], 1);
        const float mx = l[i0];
        float se = 0.0f;
#pragma unroll
        for (int j = 0; j < 8; j++) se += expf(l[j] - mx);
        mxs[tid] = mx;
        invs[tid] = 1.0f / se;
    }
    __syncthreads();
    if (tid < 8) {
        float s = 0.0f;
        for (int t = 0; t < 128; t++) s += expf(lg[t][tid] - mxs[t]) * invs[t];
        atomicAdd(&aux_sums[tid], s);
    }
    if (tid < 16) g_hist[blockIdx.x * 16 + tid] = hist[tid];
}

// ---------------------------------------------------------------------------
// Merged route-build + scatter. grid 64 x 256.
// ---------------------------------------------------------------------------
__global__ __launch_bounds__(256) void scatter_route_kernel(
    const int* __restrict__ g_hist, const int* __restrict__ top_e,
    const float* __restrict__ top_w, int* __restrict__ ntiles,
    int* __restrict__ tile_ex, int* __restrict__ list, float* __restrict__ lw) {
    __shared__ int gh[64][16];
    __shared__ int s_cnt[16], s_pre[16], s_off[16], pos[16];
    const int tid = threadIdx.x;
    for (int i = tid; i < 1024; i += 256) gh[i >> 4][i & 15] = g_hist[i];
    __syncthreads();
    if (tid < 16) {
        int run = 0, pre = 0;
        for (int b = 0; b < 64; b++) {
            if (b == (int)blockIdx.x) pre = run;
            run += gh[b][tid];
        }
        s_cnt[tid] = run;
        s_pre[tid] = pre;
    }
    __syncthreads();
    if (tid < 2) {
        const int slot = tid;
        int o = 0;
        for (int e2 = 0; e2 < 8; e2++) {
            s_off[slot * 8 + e2] = o;
            const int nt = (s_cnt[slot * 8 + e2] + 127) >> 7;
            if (blockIdx.x == 0)
                for (int t = 0; t < nt; t++) tile_ex[slot * 72 + (o >> 7) + t] = e2;
            o += nt << 7;
        }
        if (blockIdx.x == 0) ntiles[slot] = o >> 7;
    }
    __syncthreads();
    if (tid < 16) pos[tid] = s_off[tid] + s_pre[tid];
    __syncthreads();
    if (blockIdx.x == 0) {
        for (int idx = tid; idx < 16 * 128; idx += 256) {
            const int seg = idx >> 7, i = idx & 127;
            const int slot = seg >> 3;
            const int start = s_off[seg] + s_cnt[seg];
            const int end = s_off[seg] + ((s_cnt[seg] + 127) & ~127);
            const int p = start + i;
            if (p < end) {
                list[slot * 9216 + p] = 8192;
                lw[slot * 9216 + p] = 0.0f;
            }
        }
    }
    if (tid < 128) {
        const int tok = blockIdx.x * 128 + tid;
#pragma unroll
        for (int slot = 0; slot < 2; slot++) {
            const int e = top_e[slot * 8192 + tok];
            const float w = top_w[slot * 8192 + tok];
            const int idx = atomicAdd(&pos[slot * 8 + e], 1);
            list[slot * 9216 + idx] = tok;
            lw[slot * 9216 + idx] = w;
        }
    }
}

// ---------------------------------------------------------------------------
// Fused attention, one (b,h) x 32-query tile per block. grid (16,128).
// R7: exp folded into QK MFMA epilogue (registers), per-wave shuffle row
// sums -> zero softmax LDS sweeps. No max-subtraction (logits tiny; clamp
// guards overflow). 1/se applied in PV epilogue.
// ---------------------------------------------------------------------------
__global__ __launch_bounds__(256) void attn_kernel(
    const bf16* __restrict__ qkv, const bf16* __restrict__ vT,
    bf16* __restrict__ aout) {
    __shared__ alignas(16) bf16 P[32][520];
    __shared__ float wsum[4][32];
    __shared__ float sinv[32];
    const int s0 = blockIdx.x * 32;
    const int b = blockIdx.y >> 3, hh = blockIdx.y & 7;
    const int tid = threadIdx.x, wave = tid >> 6, lane = tid & 63;
    const int frow = lane & 15, fquad = lane >> 4;
    const size_t base = (size_t)b * 512;
    const float CST = 0.25505654f;  // (1/sqrt(32)) * log2(e)

    // ---- P = exp(Q K^T * scale), row partial sums per wave ----
    bf16x8 qf[2];
#pragma unroll
    for (int mt = 0; mt < 2; mt++)
        qf[mt] = *(const bf16x8*)&qkv[(base + s0 + mt * 16 + frow) * 768 + hh * 32 + fquad * 8];
    float rsum[2][4] = {};
#pragma unroll
    for (int k8 = 0; k8 < 8; k8++) {
        const int key0 = (wave * 8 + k8) * 16;
        bf16x8 kf = *(const bf16x8*)&qkv[(base + key0 + frow) * 768 + 256 + hh * 32 + fquad * 8];
#pragma unroll
        for (int mt = 0; mt < 2; mt++) {
            f32x4 c = {};
            c = __builtin_amdgcn_mfma_f32_16x16x32_bf16(qf[mt], kf, c, 0, 0, 0);
#pragma unroll
            for (int r = 0; r < 4; r++) {
                const float e_ = __builtin_exp2f(fminf(c[r] * CST, 60.0f));
                P[mt * 16 + fquad * 4 + r][key0 + frow] = (bf16)e_;
                rsum[mt][r] += e_;
            }
        }
    }
#pragma unroll
    for (int mt = 0; mt < 2; mt++)
#pragma unroll
        for (int r = 0; r < 4; r++) {
#pragma unroll
            for (int m = 1; m < 16; m <<= 1)
                rsum[mt][r] += __shfl_xor(rsum[mt][r], m, 64);
        }
    if (frow == 0) {
#pragma unroll
        for (int mt = 0; mt < 2; mt++)
#pragma unroll
            for (int r = 0; r < 4; r++)
                wsum[wave][mt * 16 + fquad * 4 + r] = rsum[mt][r];
    }
    __syncthreads();
    if (tid < 32)
        sinv[tid] = 1.0f / (wsum[0][tid] + wsum[1][tid] + wsum[2][tid] + wsum[3][tid]);

    // ---- O = (P V) * 1/se ----
    {
        const int mt = wave >> 1, nt = wave & 1;
        const bf16* vrow = &vT[((size_t)(b * 8 + hh) * 32 + nt * 16 + frow) * 512];
        f32x4 o = {};
#pragma unroll
        for (int ks = 0; ks < 16; ks++) {
            bf16x8 pf = *(const bf16x8*)&P[mt * 16 + frow][ks * 32 + fquad * 8];
            bf16x8 vf = *(const bf16x8*)&vrow[ks * 32 + fquad * 8];
            o = __builtin_amdgcn_mfma_f32_16x16x32_bf16(pf, vf, o, 0, 0, 0);
        }
        __syncthreads();
        const int r0 = mt * 16 + fquad * 4;
#pragma unroll
        for (int r = 0; r < 4; r++)
            aout[(base + s0 + r0 + r) * 256 + hh * 32 + nt * 16 + frow] =
                (bf16)(o[r] * sinv[r0 + r]);
    }
}

// ---------------------------------------------------------------------------
// Pooled attention + projection + heads.
// ---------------------------------------------------------------------------
__global__ __launch_bounds__(256) void pooled_attn_kernel(
    const bf16* __restrict__ qkv, const bf16* __restrict__ vT,
    bf16* __restrict__ pa) {
    const int wid = blockIdx.x * 4 + (threadIdx.x >> 6);
    const int lane = threadIdx.x & 63;
    const int b = wid >> 3, hh = wid & 7;
    const size_t base = (size_t)b * 512;
    const float scale = 0.17677669529663687f;
    float q[32];
#pragma unroll
    for (int d = 0; d < 32; d++) q[d] = (float)qkv[(base + 511) * 768 + hh * 32 + d];
    float sc[8];
    float mx = -1e30f;
#pragma unroll
    for (int j = 0; j < 8; j++) {
        const int key = lane + j * 64;
        const bf16* kr = &qkv[(base + key) * 768 + 256 + hh * 32];
        float s = 0.0f;
#pragma unroll
        for (int d = 0; d < 32; d++) s += q[d] * (float)kr[d];
        s *= scale;
        sc[j] = s;
        mx = fmaxf(mx, s);
    }
#pragma unroll
    for (int m = 1; m < 64; m <<= 1) mx = fmaxf(mx, __shfl_xor(mx, m, 64));
    float se = 0.0f;
#pragma unroll
    for (int j = 0; j < 8; j++) { sc[j] = expf(sc[j] - mx); se += sc[j]; }
#pragma unroll
    for (int m = 1; m < 64; m <<= 1) se += __shfl_xor(se, m, 64);
    float o[32] = {};
    const bf16* vb = &vT[(size_t)(b * 8 + hh) * 32 * 512];
#pragma unroll
    for (int d = 0; d < 32; d++) {
        const bf16* vr = vb + (size_t)d * 512;
#pragma unroll
        for (int j = 0; j < 8; j++)
            o[d] += sc[j] * (float)vr[lane + j * 64];
    }
#pragma unroll
    for (int d = 0; d < 32; d++) {
#pragma unroll
        for (int m = 1; m < 64; m <<= 1) o[d] += __shfl_xor(o[d], m, 64);
    }
    if (lane == 0) {
        const float inv = 1.0f / se;
        for (int d = 0; d < 32; d++) pa[b * 256 + hh * 32 + d] = (bf16)(o[d] * inv);
    }
}

__global__ __launch_bounds__(256) void pooled_proj_kernel(
    const bf16* __restrict__ pa, const bf16* __restrict__ w,
    const bf16* __restrict__ bias, bf16* __restrict__ pooled) {
    const int b = blockIdx.x, t = threadIdx.x;
    __shared__ float xs[256];
    xs[t] = (float)pa[b * 256 + t];
    __syncthreads();
    float acc = (float)bias[t];
    for (int k = 0; k < 256; k++) acc += xs[k] * (float)w[t * 256 + k];
    pooled[b * 256 + t] = (bf16)acc;
}

__global__ __launch_bounds__(256) void heads_kernel(
    const bf16* __restrict__ pooled,
    const bf16* __restrict__ aw1, const bf16* __restrict__ ab1,
    const bf16* __restrict__ aln1s, const bf16* __restrict__ aln1b,
    const bf16* __restrict__ aw2, const bf16* __restrict__ ab2,
    const bf16* __restrict__ aln2s, const bf16* __restrict__ aln2b,
    const bf16* __restrict__ aw3, const bf16* __restrict__ ab3,
    const bf16* __restrict__ pw1, const bf16* __restrict__ pb1,
    const bf16* __restrict__ pln1s, const bf16* __restrict__ pln1b,
    const bf16* __restrict__ pw2, const bf16* __restrict__ pb2,
    const bf16* __restrict__ pln2s, const bf16* __restrict__ pln2b,
    const bf16* __restrict__ pw3, const bf16* __restrict__ pb3,
    float* __restrict__ out) {
    const int b = blockIdx.x, t = threadIdx.x;
    __shared__ float pool[256], buf[256], buf2[256], r1[256], r2[256];
    pool[t] = (float)pooled[b * 256 + t];
    __syncthreads();

    auto block_ln = [&](float* v, int W, const bf16* ls, const bf16* lb) {
        const float val = (t < W) ? v[t] : 0.0f;
        r1[t] = val;
        r2[t] = val * val;
        __syncthreads();
        for (int off = 128; off > 0; off >>= 1) {
            if (t < off) { r1[t] += r1[t + off]; r2[t] += r2[t + off]; }
            __syncthreads();
        }
        const float mean = r1[0] / (float)W;
        const float var = fmaxf(r2[0] / (float)W - mean * mean, 0.0f);
        const float inv = rsqrtf(var + 1e-5f);
        __syncthreads();
        if (t < W) v[t] = (val - mean) * inv * (float)ls[t] + (float)lb[t];
        __syncthreads();
    };

    float a;
    if (t < 128) {
        a = (float)ab1[t];
        for (int k = 0; k < 256; k++) a += pool[k] * (float)aw1[t * 256 + k];
        buf[t] = gelu_exact(a);
    }
    __syncthreads();
    block_ln(buf, 128, aln1s, aln1b);
    if (t < 64) {
        a = (float)ab2[t];
        for (int k = 0; k < 128; k++) a += buf[k] * (float)aw2[t * 128 + k];
        buf2[t] = gelu_exact(a);
    }
    __syncthreads();
    block_ln(buf2, 64, aln2s, aln2b);
    if (t < 3) {
        a = (float)ab3[t];
        for (int k = 0; k < 64; k++) a += buf2[k] * (float)aw3[t * 64 + k];
        out[b * 3 + t] = a;
    }

    a = (float)pb1[t];
    for (int k = 0; k < 256; k++) a += pool[k] * (float)pw1[t * 256 + k];
    buf[t] = a;
    __syncthreads();
    block_ln(buf, 256, pln1s, pln1b);
    buf[t] = gelu_exact(buf[t]);
    __syncthreads();
    if (t < 128) {
        a = (float)pb2[t];
        for (int k = 0; k < 256; k++) a += buf[k] * (float)pw2[t * 256 + k];
        buf2[t] = a;
    }
    __syncthreads();
    block_ln(buf2, 128, pln2s, pln2b);
    if (t < 128) buf2[t] = gelu_exact(buf2[t]);
    __syncthreads();
    if (t == 0) {
        a = (float)pb3[0];
        for (int k = 0; k < 128; k++) a += buf2[k] * (float)pw3[k];
        out[48 + b] = a;
    }
}

__global__ void aux_kernel(const float* __restrict__ sums, float* __restrict__ out) {
    if (threadIdx.x == 0 && blockIdx.x == 0) {
        float tot = 0.0f;
        for (int l = 0; l < 6; l++)
            for (int e = 0; e < 8; e++) {
                const float mn = sums[l * 8 + e] * (1.0f / 8192.0f);
                tot += 8.0f * mn * mn;
            }
        out[64] = tot;
    }
}

// ---------------------------------------------------------------------------
extern "C" void kernel_launch(void* const* d_in, const int* in_sizes, int n_in,
                              void* d_out, int out_size, void* d_ws, size_t ws_size,
                              hipStream_t stream) {
    char* ws = (char*)d_ws;
    const size_t MB = 1024 * 1024;
    bf16*  h     = (bf16*)(ws);                        // 8193x256
    bf16*  moe0  = (bf16*)(ws + 8 * MB);               // 8193x256
    bf16*  moe1  = (bf16*)(ws + 13 * MB);              // 8193x256
    char*  ctrl  = ws + 20 * MB;
    float* auxs   = (float*)(ctrl + 0);                // 48 f32
    int*   flag   = (int*)(ctrl + 192);
    int*   ntiles = (int*)(ctrl + 256);                // [2]
    int*   tileex = (int*)(ctrl + 320);                // [2][72]
    float* ostage = (float*)(ctrl + 1024);             // 65 f32
    int*   g_hist = (int*)(ctrl + 2048);               // [64][16]
    int*   top_e  = (int*)(ctrl + 10240);              // [2][8192]
    float* top_w  = (float*)(ctrl + 75776);            // [2][8192]
    int*   list   = (int*)(ctrl + 141312);             // [2][9216]
    float* lw     = (float*)(ctrl + 215040);           // [2][9216]
    bf16*  qkv   = (bf16*)(ws + 24 * MB);              // 8192x768
    bf16*  aoutb = (bf16*)(ws + 40 * MB);              // 8192x256
    bf16*  projo = (bf16*)(ws + 48 * MB);              // 8192x256
    bf16*  hid0  = (bf16*)(ws + 56 * MB);              // 9216x1024
    bf16*  hid1  = (bf16*)(ws + 80 * MB);              // 9216x1024
    bf16*  vT    = (bf16*)(ws + 104 * MB);             // [16][8][32][512]
    bf16*  pattn  = (bf16*)(ws + 110 * MB);
    bf16*  pooled = (bf16*)(ws + 110 * MB + 8192);
    bf16*  cvbase = (bf16*)(ws + 112 * MB);            // ~10.6 MB

    InTab tab;
    unsigned off = 0;
    bf16* cv[NIN];
    for (int i = 0; i < NIN; i++) {
        tab.src[i] = d_in[i];
        tab.off[i] = off;
        tab.n[i] = (unsigned)in_sizes[i];
        cv[i] = cvbase + off;
        off += ((unsigned)in_sizes[i] + 1023u) & ~1023u;
    }
    const int cv_blocks = (int)(off >> 10);

    const bf16 *x = cv[0], *in_w = cv[1], *in_b = cv[2], *qkv_w = cv[3], *qkv_b = cv[4],
               *out_w = cv[5], *out_b = cv[6], *gate_w = cv[7], *gate_b = cv[8],
               *e_w1 = cv[9], *e_b1 = cv[10], *e_w2 = cv[11], *e_b2 = cv[12],
               *ln1_s = cv[13], *ln1_b = cv[14], *ln2_s = cv[15], *ln2_b = cv[16],
               *pqkv_w = cv[17], *pqkv_b = cv[18], *pout_w = cv[19], *pout_b = cv[20],
               *a_w1 = cv[21], *a_b1 = cv[22], *a_ln1s = cv[23], *a_ln1b = cv[24],
               *a_w2 = cv[25], *a_b2 = cv[26], *a_ln2s = cv[27], *a_ln2b = cv[28],
               *a_w3 = cv[29], *a_b3 = cv[30],
               *pr_w1 = cv[31], *pr_b1 = cv[32], *pr_ln1s = cv[33], *pr_ln1b = cv[34],
               *pr_w2 = cv[35], *pr_b2 = cv[36], *pr_ln2s = cv[37], *pr_ln2b = cv[38],
               *pr_w3 = cv[39], *pr_b3 = cv[40];

    sniff_kernel<<<1, 256, 0, stream>>>((const unsigned*)d_in[0], flag);
    convert_kernel<<<cv_blocks, 256, 0, stream>>>(tab, cvbase, flag);

    hipMemsetAsync(auxs, 0, 192, stream);
    input_proj_kernel<<<8192, 256, 0, stream>>>(x, in_w, in_b, h);

    for (int l = 0; l < 6; l++) {
        gemm_bt<64, 128, 32, 64, true><<<dim3(128, 6), 256, 0, stream>>>(
            h, qkv_w, qkv_b, qkv, 8192, 768, 256, vT);
        attn_kernel<<<dim3(16, 128), 256, 0, stream>>>(qkv, vT, aoutb);
        gemm_bt<64, 64, 32, 32, false><<<dim3(128, 4), 256, 0, stream>>>(
            aoutb, out_w, out_b, projo, 8192, 256, 256, vT);
        gate_ln_kernel<<<64, 256, 0, stream>>>(h, projo, ln1_s, ln1_b,
                                               gate_w, gate_b,
                                               top_e, top_w, g_hist, auxs + l * 8);
        scatter_route_kernel<<<64, 256, 0, stream>>>(g_hist, top_e, top_w,
                                                     ntiles, tileex, list, lw);
        gemm_moe_w1<<<dim3(142, 8), 256, 0, stream>>>(
            h, e_w1, e_b1, hid0, hid1, list, tileex, ntiles);
        gemm_moe_w2<<<dim3(142, 4), 256, 0, stream>>>(
            hid0, hid1, e_w2, e_b2, moe0, moe1, list, lw, tileex, ntiles);
        ln_kernel<<<2048, 256, 0, stream>>>(h, moe0, moe1, ln2_s, ln2_b);
    }

    gemm_bt<64, 128, 32, 64, true><<<dim3(128, 6), 256, 0, stream>>>(
        h, pqkv_w, pqkv_b, qkv, 8192, 768, 256, vT);
    pooled_attn_kernel<<<32, 256, 0, stream>>>(qkv, vT, pattn);
    pooled_proj_kernel<<<16, 256, 0, stream>>>(pattn, pout_w, pout_b, pooled);

    heads_kernel<<<16, 256, 0, stream>>>(
        pooled,
        a_w1, a_b1, a_ln1s, a_ln1b, a_w2, a_b2, a_ln2s, a_ln2b, a_w3, a_b3,
        pr_w1, pr_b1, pr_ln1s, pr_ln1b, pr_w2, pr_b2, pr_ln2s, pr_ln2b, pr_w3, pr_b3,
        ostage);
    aux_kernel<<<1, 64, 0, stream>>>(auxs, ostage);
    out_convert_kernel<<<1, 128, 0, stream>>>(ostage, d_out, flag);
}